// Round 5
// baseline (435.205 us; speedup 1.0000x reference)
//
#include <hip/hip_runtime.h>
#include <hip/hip_fp16.h>

typedef _Float16 half_t;
typedef half_t halfx8 __attribute__((ext_vector_type(8)));
typedef half_t halfx4 __attribute__((ext_vector_type(4)));
typedef float floatx4 __attribute__((ext_vector_type(4)));

#define HID 1024
#define HEADS 16
#define HD 64
#define BATCH 4
#define SEQ 2048
#define MTOT (BATCH * SEQ) /* 8192 */
#define NWELEM (HID * HID) /* 1048576 */

#define MFMA_F16 __builtin_amdgcn_mfma_f32_16x16x32_f16

// Load 8 contiguous elements as halfx8; fp32 source converts on the fly.
__device__ inline halfx8 load8h(const half_t* p) { return *(const halfx8*)p; }
__device__ inline halfx8 load8h(const float* p) {
    floatx4 x = *(const floatx4*)p;
    floatx4 y = *(const floatx4*)(p + 4);
    halfx8 r;
    r[0] = (half_t)x[0]; r[1] = (half_t)x[1];
    r[2] = (half_t)x[2]; r[3] = (half_t)x[3];
    r[4] = (half_t)y[0]; r[5] = (half_t)y[1];
    r[6] = (half_t)y[2]; r[7] = (half_t)y[3];
    return r;
}

// pack two fp32 -> one dword of 2 fp16 (RTN, matches (half_t) cast numerics)
__device__ __forceinline__ uint32_t pack2h(float a, float b) {
    union { half_t h[2]; uint32_t u; } r;
    r.h[0] = (half_t)a; r.h[1] = (half_t)b;
    return r.u;
}

// async 16B global->LDS: LDS dest is wave-uniform base + lane*16 (m104/m173);
// global src is per-lane. size arg must be a literal (16).
__device__ __forceinline__ void gl_lds16(const half_t* g, half_t* lds) {
    __builtin_amdgcn_global_load_lds(
        (const __attribute__((address_space(1))) void*)g,
        (__attribute__((address_space(3))) void*)lds, 16, 0, 0);
}

// ---------------------------------------------------------------------------
// GEMM epilogues.  C/D layout: col = lane&15, row = quad*4 + reg
// [m89-verified].
// mode 0: fp16 -> [B][H][S][D]   (Q, K)
// mode 2: fp16 -> [B][H][D][S]   (V transposed; 8B-aligned halfx4 stores)
// MODE 1 (template): fp32 -> flat [M, N]  (final)
// ---------------------------------------------------------------------------
__device__ __forceinline__ void epilogue_qkv(
    const floatx4 (&acc)[4][4], const float* __restrict__ bias, int mode,
    half_t* __restrict__ Out, int m0, int n0, int wm, int wn, int quad, int l16)
{
    float bvals[4];
#pragma unroll
    for (int nt = 0; nt < 4; ++nt)
        bvals[nt] = bias[n0 + wn + nt * 16 + l16];

#pragma unroll
    for (int mt = 0; mt < 4; ++mt) {
        const int mbase = m0 + wm + mt * 16 + quad * 4;
#pragma unroll
        for (int nt = 0; nt < 4; ++nt) {
            const int n = n0 + wn + nt * 16 + l16;
            if (mode == 2) {
                const int b = mbase >> 11, s = mbase & (SEQ - 1);
                const int h = n >> 6, d = n & (HD - 1);
                halfx4 st;
#pragma unroll
                for (int r = 0; r < 4; ++r)
                    st[r] = (half_t)(acc[mt][nt][r] + bvals[nt]);
                *(halfx4*)(Out +
                    ((((size_t)b * HEADS + h) * HD + d) << 11) + s) = st;
            } else {
#pragma unroll
                for (int r = 0; r < 4; ++r) {
                    const float v = acc[mt][nt][r] + bvals[nt];
                    const int mm  = mbase + r;
                    const int b = mm >> 11, s = mm & (SEQ - 1);
                    const int h = n >> 6, d = n & (HD - 1);
                    Out[((((size_t)b * HEADS + h) * SEQ + s) << 6) + d] = (half_t)v;
                }
            }
        }
    }
}

template <typename TOut>
__device__ __forceinline__ void epilogue_flat(
    const floatx4 (&acc)[4][4], const float* __restrict__ bias,
    TOut* __restrict__ Out, int m0, int n0, int wm, int wn, int quad, int l16)
{
    float bvals[4];
#pragma unroll
    for (int nt = 0; nt < 4; ++nt)
        bvals[nt] = bias[n0 + wn + nt * 16 + l16];
#pragma unroll
    for (int mt = 0; mt < 4; ++mt) {
        const int mbase = m0 + wm + mt * 16 + quad * 4;
#pragma unroll
        for (int nt = 0; nt < 4; ++nt) {
            const int n = n0 + wn + nt * 16 + l16;
#pragma unroll
            for (int r = 0; r < 4; ++r)
                Out[(size_t)(mbase + r) * HID + n] =
                    (TOut)(acc[mt][nt][r] + bvals[nt]);
        }
    }
}

// ---------------------------------------------------------------------------
// Shared GEMM K-loop body (fp16 A and W): 128x128 tile, BK=32, 256 thr
// (4 waves 2x2), mfma 16x16x32 f16, 2-phase double-buffered LDS staged via
// global_load_lds width=16.  XCD swizzle within a 512-block slice.
// ---------------------------------------------------------------------------
struct GemmCtx {
    int m0, n0, wm, wn, quad, l16;
};

template <typename EPI>
__device__ __forceinline__ void gemm_body(
    const half_t* __restrict__ A, const half_t* __restrict__ W,
    half_t* As, half_t* Bs,   // [2][128*32] each, passed as flat
    EPI&& epi)
{
    const int tid  = threadIdx.x;
    const int id   = blockIdx.y * gridDim.x + blockIdx.x;   // 0..511 per slice
    const int cpx  = (gridDim.x * gridDim.y) >> 3;
    const int swz  = (id & 7) * cpx + (id >> 3);
    const int m0   = (swz >> 3) * 128;          // gridDim.x == 8
    const int n0   = (swz & 7) * 128;
    const int wave = tid >> 6;
    const int lane = tid & 63;
    const int quad = lane >> 4;
    const int l16  = lane & 15;
    const int wm   = (wave >> 1) * 64;
    const int wn   = (wave & 1) * 64;

    // staging map: wave w owns chunks 2w,2w+1 (16 rows each) of A and B.
    const int c0   = wave * 2;
    const int srow = c0 * 16 + (lane >> 2);
    const int scol = (lane & 3) * 8;
    const half_t* aptr0 = A + (size_t)(m0 + srow) * HID + scol;
    const half_t* aptr1 = aptr0 + (size_t)16 * HID;
    const half_t* bptr0 = W + (size_t)(n0 + srow) * HID + scol;
    const half_t* bptr1 = bptr0 + (size_t)16 * HID;

    floatx4 acc[4][4];
    const floatx4 zero4 = {0.f, 0.f, 0.f, 0.f};
#pragma unroll
    for (int mt = 0; mt < 4; ++mt)
#pragma unroll
        for (int nt = 0; nt < 4; ++nt) acc[mt][nt] = zero4;

    auto stage = [&](int buf, int k0) {
        gl_lds16(aptr0 + k0, &As[buf * 4096 + c0 * 512]);
        gl_lds16(aptr1 + k0, &As[buf * 4096 + c0 * 512 + 512]);
        gl_lds16(bptr0 + k0, &Bs[buf * 4096 + c0 * 512]);
        gl_lds16(bptr1 + k0, &Bs[buf * 4096 + c0 * 512 + 512]);
    };
    auto compute = [&](int buf) {
        halfx8 af[4], bfr[4];
#pragma unroll
        for (int t = 0; t < 4; ++t) {
            af[t]  = *(const halfx8*)&As[buf * 4096 + (wm + t * 16 + l16) * 32 + quad * 8];
            bfr[t] = *(const halfx8*)&Bs[buf * 4096 + (wn + t * 16 + l16) * 32 + quad * 8];
        }
#pragma unroll
        for (int mt = 0; mt < 4; ++mt)
#pragma unroll
            for (int nt = 0; nt < 4; ++nt)
                acc[mt][nt] = MFMA_F16(af[mt], bfr[nt], acc[mt][nt], 0, 0, 0);
    };

    stage(0, 0);
    __syncthreads();              // implicit vmcnt(0): tile 0 resident
    for (int k0 = 0; k0 < HID; k0 += 64) {
        stage(1, k0 + 32);        // prefetch while computing buf 0
        compute(0);
        __syncthreads();          // drain: prefetch landed; buf0 reads done
        if (k0 + 64 < HID) stage(0, k0 + 64);
        compute(1);
        __syncthreads();
    }

    GemmCtx c{m0, n0, wm, wn, quad, l16};
    epi(acc, c);
}

// Fused QKV projection: blockIdx.z selects (A, W, bias, Out, mode).
// grid (8, 64, 3) = 1536 blocks -> ~5 blocks/CU co-resident (LDS 32KB):
// cross-block MFMA/staging overlap (m114) that R4's 512-block grid lacked.
__global__ __launch_bounds__(256) void gemm_qkv(
    const half_t* __restrict__ q16, const half_t* __restrict__ k16,
    const half_t* __restrict__ v16, const half_t* __restrict__ W16,
    const float* __restrict__ bq, const float* __restrict__ bk,
    const float* __restrict__ bv,
    half_t* __restrict__ Qp, half_t* __restrict__ Kp, half_t* __restrict__ VpT)
{
    __shared__ half_t As[2 * 128 * 32];
    __shared__ half_t Bs[2 * 128 * 32];

    const int z = blockIdx.z;
    const half_t* A    = (z == 0) ? q16 : (z == 1) ? k16 : v16;
    const half_t* W    = W16 + (size_t)z * NWELEM;
    const float*  bias = (z == 0) ? bq : (z == 1) ? bk : bv;
    half_t*       Out  = (z == 0) ? Qp : (z == 1) ? Kp : VpT;
    const int     mode = (z == 2) ? 2 : 0;

    gemm_body(A, W, As, Bs,
        [&](const floatx4 (&acc)[4][4], const GemmCtx& c) {
            epilogue_qkv(acc, bias, mode, Out, c.m0, c.n0, c.wm, c.wn,
                         c.quad, c.l16);
        });
}

// Final projection: Ob(fp16) @ Wo^T + bo -> fp32 flat.
__global__ __launch_bounds__(256) void gemm_final(
    const half_t* __restrict__ A, const half_t* __restrict__ W,
    const float* __restrict__ bias, float* __restrict__ Out)
{
    __shared__ half_t As[2 * 128 * 32];
    __shared__ half_t Bs[2 * 128 * 32];
    gemm_body(A, W, As, Bs,
        [&](const floatx4 (&acc)[4][4], const GemmCtx& c) {
            epilogue_flat(acc, bias, Out, c.m0, c.n0, c.wm, c.wn,
                          c.quad, c.l16);
        });
}

// ---------------------------------------------------------------------------
// Legacy GEMM (fp32 A/W, reg-staged cvt) — fallback if ws too small for the
// fp16 pre-convert path.
// ---------------------------------------------------------------------------
template <int MODE, typename TA, typename TOut>
__global__ __launch_bounds__(256) void gemm_bt(
    const TA* __restrict__ A, const float* __restrict__ W,
    const float* __restrict__ bias, TOut* __restrict__ Out)
{
    __shared__ half_t As[128][40];
    __shared__ half_t Bs[128][40];

    const int tid  = threadIdx.x;
    const int m0   = blockIdx.y * 128;
    const int n0   = blockIdx.x * 128;
    const int wave = tid >> 6;
    const int lane = tid & 63;
    const int quad = lane >> 4;
    const int l16  = lane & 15;
    const int wm   = (wave >> 1) * 64;
    const int wn   = (wave & 1) * 64;
    const int trow = tid >> 1;
    const int tcol = (tid & 1) * 16;

    const TA*    aptr = A + (size_t)(m0 + trow) * HID + tcol;
    const float* bptr = W + (size_t)(n0 + trow) * HID + tcol;

    floatx4 acc[4][4];
    const floatx4 zero4 = {0.f, 0.f, 0.f, 0.f};
#pragma unroll
    for (int mt = 0; mt < 4; ++mt)
#pragma unroll
        for (int nt = 0; nt < 4; ++nt) acc[mt][nt] = zero4;

    for (int k0 = 0; k0 < HID; k0 += 32) {
        halfx8 av0 = load8h(aptr);
        halfx8 av1 = load8h(aptr + 8);
        halfx8 bv0 = load8h(bptr);
        halfx8 bv1 = load8h(bptr + 8);
        aptr += 32;
        bptr += 32;

        __syncthreads();
        *(halfx8*)&As[trow][tcol]     = av0;
        *(halfx8*)&As[trow][tcol + 8] = av1;
        *(halfx8*)&Bs[trow][tcol]     = bv0;
        *(halfx8*)&Bs[trow][tcol + 8] = bv1;
        __syncthreads();

        halfx8 af[4], bfr[4];
#pragma unroll
        for (int t = 0; t < 4; ++t) {
            af[t]  = *(const halfx8*)&As[wm + t * 16 + l16][quad * 8];
            bfr[t] = *(const halfx8*)&Bs[wn + t * 16 + l16][quad * 8];
        }
#pragma unroll
        for (int mt = 0; mt < 4; ++mt)
#pragma unroll
            for (int nt = 0; nt < 4; ++nt)
                acc[mt][nt] = MFMA_F16(af[mt], bfr[nt], acc[mt][nt], 0, 0, 0);
    }

    // epilogue (same as pre-R5 template version)
    float bvals[4];
#pragma unroll
    for (int nt = 0; nt < 4; ++nt)
        bvals[nt] = bias[n0 + wn + nt * 16 + l16];
#pragma unroll
    for (int mt = 0; mt < 4; ++mt) {
        const int mbase = m0 + wm + mt * 16 + quad * 4;
#pragma unroll
        for (int nt = 0; nt < 4; ++nt) {
            const int n = n0 + wn + nt * 16 + l16;
            if (MODE == 2) {
                const int b = mbase >> 11, s = mbase & (SEQ - 1);
                const int h = n >> 6, d = n & (HD - 1);
                halfx4 st;
#pragma unroll
                for (int r = 0; r < 4; ++r)
                    st[r] = (half_t)(acc[mt][nt][r] + bvals[nt]);
                *(halfx4*)((half_t*)Out +
                    ((((size_t)b * HEADS + h) * HD + d) << 11) + s) = st;
            } else {
#pragma unroll
                for (int r = 0; r < 4; ++r) {
                    const float v = acc[mt][nt][r] + bvals[nt];
                    const int mm  = mbase + r;
                    if (MODE == 0) {
                        const int b = mm >> 11, s = mm & (SEQ - 1);
                        const int h = n >> 6, d = n & (HD - 1);
                        Out[((((size_t)b * HEADS + h) * SEQ + s) << 6) + d] = (TOut)v;
                    } else {
                        Out[(size_t)mm * HID + n] = (TOut)v;
                    }
                }
            }
        }
    }
}

// ---------------------------------------------------------------------------
// fp32 -> fp16 conversion kernels (memory-bound, vectorized 8/thread).
// cvt_act3: one launch converts q, k, v (blockIdx.y selects).
// ---------------------------------------------------------------------------
__global__ __launch_bounds__(256) void cvt_act3(
    const float* __restrict__ q, const float* __restrict__ k,
    const float* __restrict__ v,
    half_t* __restrict__ q16, half_t* __restrict__ k16, half_t* __restrict__ v16)
{
    const int t = blockIdx.y;
    const float* src = (t == 0) ? q : (t == 1) ? k : v;
    half_t* dst = (t == 0) ? q16 : (t == 1) ? k16 : v16;
    const size_t i = ((size_t)blockIdx.x * 256 + threadIdx.x) * 8;
    *(halfx8*)(dst + i) = load8h(src + i);
}

__global__ __launch_bounds__(256) void cvt_w4(
    const float* __restrict__ w0, const float* __restrict__ w1,
    const float* __restrict__ w2, const float* __restrict__ w3,
    half_t* __restrict__ out)
{
    const int t = blockIdx.y;
    const float* src = (t == 0) ? w0 : (t == 1) ? w1 : (t == 2) ? w2 : w3;
    const size_t i = ((size_t)blockIdx.x * 256 + threadIdx.x) * 8;
    *(halfx8*)(out + (size_t)t * NWELEM + i) = load8h(src + i);
}

// ---------------------------------------------------------------------------
// Causal flash attention, fp16, swapped-QK^T (in-register softmax), with
// R2-proven shfl-based cross-lane ops, + T13 defer-max + T14 async staging.
// UNCHANGED from R4 (proven 101 us).
// ---------------------------------------------------------------------------
__global__ __launch_bounds__(256) void attn_kernel(
    const half_t* __restrict__ Q, const half_t* __restrict__ K,
    const half_t* __restrict__ VT, half_t* __restrict__ O)
{
    __shared__ half_t Ks[64][72];      // [k][d]
    __shared__ half_t Vt[64][72];      // [d][k]

    const int bh  = blockIdx.x;                      // b*HEADS + h
    const int qt  = (gridDim.y - 1) - blockIdx.y;    // heaviest tiles first
    const int q0  = qt * 128;
    const int tid = threadIdx.x;
    const int wave = tid >> 6;
    const int lane = tid & 63;
    const int quad = lane >> 4;
    const int l16  = lane & 15;

    const half_t* Qb  = Q  + (size_t)bh * SEQ * HD;
    const half_t* Kb  = K  + (size_t)bh * SEQ * HD;
    const half_t* VTb = VT + (size_t)bh * HD * SEQ;

    // Q fragments (B-operand of swapped QK^T): B[n=q=l16][k=d=quad*8+j]
    halfx8 aq[2][2];
#pragma unroll
    for (int mt = 0; mt < 2; ++mt) {
        const half_t* p = Qb + (size_t)(q0 + wave * 32 + mt * 16 + l16) * HD + quad * 8;
        aq[mt][0] = *(const halfx8*)p;
        aq[mt][1] = *(const halfx8*)(p + 32);
    }

    const floatx4 zero4 = {0.f, 0.f, 0.f, 0.f};
    floatx4 oaccT[2][4];   // [mt][dt]: lane holds O[q=mt*16+l16][d=dt*16+quad*4+r]
    float mrow[2], lrow[2];
#pragma unroll
    for (int mt = 0; mt < 2; ++mt) {
        mrow[mt] = -3.0e38f;
        lrow[mt] = 0.f;
#pragma unroll
        for (int dt = 0; dt < 4; ++dt) oaccT[mt][dt] = zero4;
    }

    const int srow = tid >> 2;         // 0..63
    const int scol = (tid & 3) * 16;   // 0,16,32,48
    const int ktiles = 2 * qt + 2;

    union U8 { halfx8 h; uint32_t u[4]; };

    // T14 prologue: tile 0 K/V -> regs
    halfx8 nk0, nk1, nv0, nv1;
    {
        const half_t* ksrc = Kb + (size_t)srow * HD + scol;
        nk0 = *(const halfx8*)ksrc;
        nk1 = *(const halfx8*)(ksrc + 8);
        const half_t* vsrc = VTb + (size_t)srow * SEQ + scol;
        nv0 = *(const halfx8*)vsrc;
        nv1 = *(const halfx8*)(vsrc + 8);
    }

    for (int kt = 0; kt < ktiles; ++kt) {
        const int k0 = kt * 64;
        __syncthreads();  // prior iter's Ks/Vt reads done
        *(halfx8*)&Ks[srow][scol]     = nk0;
        *(halfx8*)&Ks[srow][scol + 8] = nk1;
        *(halfx8*)&Vt[srow][scol]     = nv0;
        *(halfx8*)&Vt[srow][scol + 8] = nv1;
        __syncthreads();

        // T14: issue next tile's global loads before this tile's compute
        if (kt + 1 < ktiles) {
            const int kn = k0 + 64;
            const half_t* ksrc = Kb + (size_t)(kn + srow) * HD + scol;
            nk0 = *(const halfx8*)ksrc;
            nk1 = *(const halfx8*)(ksrc + 8);
            const half_t* vsrc = VTb + (size_t)srow * SEQ + kn + scol;
            nv0 = *(const halfx8*)vsrc;
            nv1 = *(const halfx8*)(vsrc + 8);
        }

        // wave-uniform activity predicate (no continue: barriers stay uniform)
        const bool active = (k0 <= q0 + wave * 32 + 31);

        if (active) {
            // S^T: sacc[mt][nt] rows kv, cols q (swapped operands)
            floatx4 sacc[2][4];
#pragma unroll
            for (int mt = 0; mt < 2; ++mt)
#pragma unroll
                for (int nt = 0; nt < 4; ++nt) sacc[mt][nt] = zero4;
#pragma unroll
            for (int nt = 0; nt < 4; ++nt) {
                halfx8 bk0 = *(const halfx8*)&Ks[nt * 16 + l16][quad * 8];
                halfx8 bk1 = *(const halfx8*)&Ks[nt * 16 + l16][quad * 8 + 32];
#pragma unroll
                for (int mt = 0; mt < 2; ++mt) {
                    sacc[mt][nt] = MFMA_F16(bk0, aq[mt][0], sacc[mt][nt], 0, 0, 0);
                    sacc[mt][nt] = MFMA_F16(bk1, aq[mt][1], sacc[mt][nt], 0, 0, 0);
                }
            }

            if (kt >= 2 * qt) {  // diagonal region: mask kv > q
#pragma unroll
                for (int mt = 0; mt < 2; ++mt) {
                    const int qg = q0 + wave * 32 + mt * 16 + l16;
#pragma unroll
                    for (int nt = 0; nt < 4; ++nt) {
                        const int kg = k0 + nt * 16 + quad * 4;
#pragma unroll
                        for (int r = 0; r < 4; ++r)
                            if (kg + r > qg) sacc[mt][nt][r] = -1.0e30f;
                    }
                }
            }

            // in-register online softmax (per lane = per q row, 16 vals)
            uint32_t pk[2][4][2];
#pragma unroll
            for (int mt = 0; mt < 2; ++mt) {
                float mx = sacc[mt][0][0];
#pragma unroll
                for (int nt = 0; nt < 4; ++nt)
#pragma unroll
                    for (int r = 0; r < 4; ++r)
                        if (nt | r) mx = fmaxf(mx, sacc[mt][nt][r]);
                mx = fmaxf(mx, __shfl_xor(mx, 16));
                mx = fmaxf(mx, __shfl_xor(mx, 32));

                // T13 defer-max: skip rescale while tile max lags running
                // max by <= 8 (P <= e^8 = 2981 fits fp16; fp32 accum).
                if (!__all(mx <= mrow[mt] + 8.f)) {
                    const float mnew  = fmaxf(mrow[mt], mx);
                    const float alpha = __expf(mrow[mt] - mnew);
                    mrow[mt] = mnew;
                    lrow[mt] *= alpha;
#pragma unroll
                    for (int dt = 0; dt < 4; ++dt) oaccT[mt][dt] *= alpha;
                }

                float rsum = 0.f;
#pragma unroll
                for (int nt = 0; nt < 4; ++nt)
#pragma unroll
                    for (int r = 0; r < 4; ++r) {
                        const float p = __expf(sacc[mt][nt][r] - mrow[mt]);
                        sacc[mt][nt][r] = p;
                        rsum += p;
                    }
#pragma unroll
                for (int nt = 0; nt < 4; ++nt) {
                    pk[mt][nt][0] = pack2h(sacc[mt][nt][0], sacc[mt][nt][1]);
                    pk[mt][nt][1] = pack2h(sacc[mt][nt][2], sacc[mt][nt][3]);
                }
                rsum += __shfl_xor(rsum, 16);
                rsum += __shfl_xor(rsum, 32);
                lrow[mt] += rsum;
            }

            // redistribute P^T C-layout -> PV B-frag [n=q=l16][k=kv=quad*8+j].
            // (R2-proven shfl mapping.)
            U8 pb[2][2];  // [mt][s2]
#pragma unroll
            for (int mt = 0; mt < 2; ++mt)
#pragma unroll
                for (int s2 = 0; s2 < 2; ++s2)
#pragma unroll
                    for (int w = 0; w < 4; ++w) {
                        const int src = l16 + ((quad & 1) << 5) + ((w >> 1) << 4);
                        const uint32_t lo =
                            (uint32_t)__shfl((int)pk[mt][2 * s2][w & 1], src, 64);
                        const uint32_t hi =
                            (uint32_t)__shfl((int)pk[mt][2 * s2 + 1][w & 1], src, 64);
                        pb[mt][s2].u[w] = (quad >> 1) ? hi : lo;
                    }

            // PV: O^T = MFMA(A=V^T frag, B=P frag)
#pragma unroll
            for (int s2 = 0; s2 < 2; ++s2)
#pragma unroll
                for (int dt = 0; dt < 4; ++dt) {
                    halfx8 bv = *(const halfx8*)&Vt[dt * 16 + l16][s2 * 32 + quad * 8];
                    oaccT[0][dt] = MFMA_F16(bv, pb[0][s2].h, oaccT[0][dt], 0, 0, 0);
                    oaccT[1][dt] = MFMA_F16(bv, pb[1][s2].h, oaccT[1][dt], 0, 0, 0);
                }
        }
    }

    // epilogue: O^T fragment -> Ob[b][q][h*64+d], halfx4 along d
    const int b = bh >> 4, h = bh & (HEADS - 1);
#pragma unroll
    for (int mt = 0; mt < 2; ++mt) {
        const int q = q0 + wave * 32 + mt * 16 + l16;
#pragma unroll
        for (int dt = 0; dt < 4; ++dt) {
            halfx4 st;
#pragma unroll
            for (int r = 0; r < 4; ++r)
                st[r] = (half_t)(oaccT[mt][dt][r] / lrow[mt]);
            *(halfx4*)(O + (size_t)(b * SEQ + q) * HID +
                       h * HD + dt * 16 + quad * 4) = st;
        }
    }
}

// ---------------------------------------------------------------------------
extern "C" void kernel_launch(void* const* d_in, const int* in_sizes, int n_in,
                              void* d_out, int out_size, void* d_ws, size_t ws_size,
                              hipStream_t stream)
{
    const float* query = (const float*)d_in[0];
    const float* key   = (const float*)d_in[1];
    const float* value = (const float*)d_in[2];
    const float* Wq    = (const float*)d_in[3];
    const float* bq    = (const float*)d_in[4];
    const float* Wk    = (const float*)d_in[5];
    const float* bk    = (const float*)d_in[6];
    const float* Wv    = (const float*)d_in[7];
    const float* bv    = (const float*)d_in[8];
    const float* Wo    = (const float*)d_in[9];
    const float* bo    = (const float*)d_in[10];
    float* out = (float*)d_out;

    // workspace (fp16): Qp, Kp [B][H][S][D]; VpT [B][H][D][S]; Ob [M][HID];
    // W16 [4][HID][HID] = 75.5 MB (proven R1-R4).  Concurrent-QKV needs all
    // three fp16 activations live at once: q16/k16 live in d_out used as
    // scratch (2*NE*2B == out_size exactly; d_out is dead until gemm_final
    // rewrites every element), v16 takes the Ob slot (dead until attn).
    const size_t NE = (size_t)MTOT * HID;
    half_t* Qp  = (half_t*)d_ws;
    half_t* Kp  = Qp  + NE;
    half_t* VpT = Kp  + NE;
    half_t* Ob  = VpT + NE;
    half_t* W16 = Ob  + NE;
    const size_t need = (4 * NE + 4 * (size_t)NWELEM) * sizeof(half_t);

    dim3 gg(HID / 128, MTOT / 128);     // (8, 64)
    dim3 ga(BATCH * HEADS, SEQ / 128);  // (64, 16)

    if (ws_size >= need && (size_t)out_size >= 2 * NE * sizeof(half_t)) {
        half_t* q16 = (half_t*)out;       // d_out scratch
        half_t* k16 = q16 + NE;
        half_t* v16 = Ob;                 // Ob slot scratch
        const unsigned actBlocks = (unsigned)(NE / 2048);      // 4096
        const unsigned wBlocks   = (unsigned)(NWELEM / 2048);  // 512

        cvt_w4<<<dim3(wBlocks, 4), 256, 0, stream>>>(Wq, Wk, Wv, Wo, W16);
        cvt_act3<<<dim3(actBlocks, 3), 256, 0, stream>>>(
            query, key, value, q16, k16, v16);

        gemm_qkv<<<dim3(8, 64, 3), 256, 0, stream>>>(
            q16, k16, v16, W16, bq, bk, bv, Qp, Kp, VpT);

        attn_kernel<<<ga, 256, 0, stream>>>(Qp, Kp, VpT, Ob);

        gemm_final<<<gg, 256, 0, stream>>>(Ob, W16 + 3 * (size_t)NWELEM, bo, out);
    } else {
        // legacy fallback path
        gemm_bt<0, float, half_t><<<gg, 256, 0, stream>>>(query, Wq, bq, Qp);
        gemm_bt<0, float, half_t><<<gg, 256, 0, stream>>>(key,   Wk, bk, Kp);
        gemm_bt<2, float, half_t><<<gg, 256, 0, stream>>>(value, Wv, bv, VpT);
        attn_kernel<<<ga, 256, 0, stream>>>(Qp, Kp, VpT, Ob);
        gemm_bt<1, half_t, float><<<gg, 256, 0, stream>>>(Ob, Wo, bo, out);
    }
}

// Round 6
// 434.176 us; speedup vs baseline: 1.0024x; 1.0024x over previous
//
#include <hip/hip_runtime.h>
#include <hip/hip_fp16.h>

typedef _Float16 half_t;
typedef half_t halfx8 __attribute__((ext_vector_type(8)));
typedef half_t halfx4 __attribute__((ext_vector_type(4)));
typedef float floatx4 __attribute__((ext_vector_type(4)));

#define HID 1024
#define HEADS 16
#define HD 64
#define BATCH 4
#define SEQ 2048
#define MTOT (BATCH * SEQ) /* 8192 */
#define NWELEM (HID * HID) /* 1048576 */

#define MFMA_F16 __builtin_amdgcn_mfma_f32_16x16x32_f16

// Load 8 contiguous elements as halfx8; fp32 source converts on the fly.
__device__ inline halfx8 load8h(const half_t* p) { return *(const halfx8*)p; }
__device__ inline halfx8 load8h(const float* p) {
    floatx4 x = *(const floatx4*)p;
    floatx4 y = *(const floatx4*)(p + 4);
    halfx8 r;
    r[0] = (half_t)x[0]; r[1] = (half_t)x[1];
    r[2] = (half_t)x[2]; r[3] = (half_t)x[3];
    r[4] = (half_t)y[0]; r[5] = (half_t)y[1];
    r[6] = (half_t)y[2]; r[7] = (half_t)y[3];
    return r;
}

// pack two fp32 -> one dword of 2 fp16 (RTN, matches (half_t) cast numerics)
__device__ __forceinline__ uint32_t pack2h(float a, float b) {
    union { half_t h[2]; uint32_t u; } r;
    r.h[0] = (half_t)a; r.h[1] = (half_t)b;
    return r.u;
}

// async 16B global->LDS: LDS dest is wave-uniform base + lane*16 (m104/m173);
// global src is per-lane. size arg must be a literal (16).
__device__ __forceinline__ void gl_lds16(const half_t* g, half_t* lds) {
    __builtin_amdgcn_global_load_lds(
        (const __attribute__((address_space(1))) void*)g,
        (__attribute__((address_space(3))) void*)lds, 16, 0, 0);
}

// ---------------------------------------------------------------------------
// Shared GEMM epilogue.  C/D layout: col = lane&15, row = quad*4 + reg
// [m89-verified].
// MODE 0: fp16 -> [B][H][S][D]   (Q, K)
// MODE 1: fp32 -> flat [M, N]    (final)
// MODE 2: fp16 -> [B][H][D][S]   (V transposed; 8B-aligned halfx4 stores)
// ---------------------------------------------------------------------------
template <int MODE, typename TOut>
__device__ __forceinline__ void epilogue_store(
    const floatx4 (&acc)[4][4], const float* __restrict__ bias,
    TOut* __restrict__ Out, int m0, int n0, int wm, int wn, int quad, int l16)
{
    float bvals[4];
#pragma unroll
    for (int nt = 0; nt < 4; ++nt)
        bvals[nt] = bias[n0 + wn + nt * 16 + l16];

#pragma unroll
    for (int mt = 0; mt < 4; ++mt) {
        const int mbase = m0 + wm + mt * 16 + quad * 4;
#pragma unroll
        for (int nt = 0; nt < 4; ++nt) {
            const int n = n0 + wn + nt * 16 + l16;
            if (MODE == 2) {
                const int b = mbase >> 11, s = mbase & (SEQ - 1);
                const int h = n >> 6, d = n & (HD - 1);
                halfx4 st;
#pragma unroll
                for (int r = 0; r < 4; ++r)
                    st[r] = (half_t)(acc[mt][nt][r] + bvals[nt]);
                *(halfx4*)((half_t*)Out +
                    ((((size_t)b * HEADS + h) * HD + d) << 11) + s) = st;
            } else {
#pragma unroll
                for (int r = 0; r < 4; ++r) {
                    const float v = acc[mt][nt][r] + bvals[nt];
                    const int mm  = mbase + r;
                    if (MODE == 0) {
                        const int b = mm >> 11, s = mm & (SEQ - 1);
                        const int h = n >> 6, d = n & (HD - 1);
                        Out[((((size_t)b * HEADS + h) * SEQ + s) << 6) + d] = (TOut)v;
                    } else {
                        Out[(size_t)mm * HID + n] = (TOut)v;
                    }
                }
            }
        }
    }
}

// ---------------------------------------------------------------------------
// Fast GEMM (fp16 A and W): Out = A @ W^T + bias.
// 128x128 tile, BK=64 (NEW), 256 thr (4 waves 2x2), mfma 16x16x32 f16,
// 2-phase double-buffered LDS (2 x 128x64 halfs per matrix = 64 KB total).
// Barriers: 16 per GEMM (vs 32 at BK=32) -> exposed HBM drain per barrier
// amortized over 2x the MFMA work.
//
// T2 XOR swizzle (rule #21: both-sides-or-neither with global_load_lds):
// LDS stays LINEAR (gl_lds writes base+lane*16); the per-lane GLOBAL source
// column is pre-swizzled (slot = (lane&7) ^ (lane>>3)), and fragment reads
// XOR the same pattern (col ^= (row&7)<<3 halfs).  Without this, row stride
// 128 B makes ds_read_b128 16-way bank-conflicted; with it, each quad's 16
// lanes spread 2-per-16B-slot (free, m136).
// XCD swizzle: nwg=512 (%8==0); per-XCD footprint = A-panel 2MB + W 2MB =
// 4MB = one L2 (this is why R5's z-fusion thrashed: 3 Ws per XCD).
// ---------------------------------------------------------------------------
struct GemmCtx { int m0, n0, wm, wn, quad, l16; };

template <typename EPI>
__device__ __forceinline__ void gemm_body(
    const half_t* __restrict__ A, const half_t* __restrict__ W,
    half_t* As, half_t* Bs,   // [2][128*64] each, flat
    EPI&& epi)
{
    const int tid  = threadIdx.x;
    const int id   = blockIdx.y * gridDim.x + blockIdx.x;
    const int cpx  = (gridDim.x * gridDim.y) >> 3;
    const int swz  = (id & 7) * cpx + (id >> 3);
    const int m0   = (swz >> 3) * 128;          // gridDim.x == 8
    const int n0   = (swz & 7) * 128;
    const int wave = tid >> 6;
    const int lane = tid & 63;
    const int quad = lane >> 4;
    const int l16  = lane & 15;
    const int wm   = (wave >> 1) * 64;
    const int wn   = (wave & 1) * 64;

    // staging map (BK=64): wave w stages rows [32w, 32w+32) of A and B as
    // 4 chunks x 8 rows.  lane -> row chunkbase + (lane>>3), global col slot
    // ((lane&7) ^ (lane>>3)) * 8 halfs (inverse-swizzled source).
    const int r8   = lane >> 3;              // row within chunk, == row&7
    const int slot = (lane & 7) ^ r8;        // pre-swizzled 16B slot
    const int srow = wave * 32 + r8;
    const half_t* aP = A + (size_t)(m0 + srow) * HID + slot * 8;
    const half_t* bP = W + (size_t)(n0 + srow) * HID + slot * 8;

    floatx4 acc[4][4];
    const floatx4 zero4 = {0.f, 0.f, 0.f, 0.f};
#pragma unroll
    for (int mt = 0; mt < 4; ++mt)
#pragma unroll
        for (int nt = 0; nt < 4; ++nt) acc[mt][nt] = zero4;

    auto stage = [&](int buf, int k0) {
#pragma unroll
        for (int c = 0; c < 4; ++c) {
            gl_lds16(aP + (size_t)(8 * c) * HID + k0,
                     &As[buf * 8192 + (wave * 32 + 8 * c) * 64]);
            gl_lds16(bP + (size_t)(8 * c) * HID + k0,
                     &Bs[buf * 8192 + (wave * 32 + 8 * c) * 64]);
        }
    };
    auto compute = [&](int buf) {
#pragma unroll
        for (int ks = 0; ks < 2; ++ks) {
            halfx8 af[4], bfr[4];
#pragma unroll
            for (int t = 0; t < 4; ++t) {
                const int ra = wm + t * 16 + l16;
                af[t]  = *(const halfx8*)&As[buf * 8192 + ra * 64 +
                          ((ks * 32 + quad * 8) ^ ((ra & 7) << 3))];
                const int rb = wn + t * 16 + l16;
                bfr[t] = *(const halfx8*)&Bs[buf * 8192 + rb * 64 +
                          ((ks * 32 + quad * 8) ^ ((rb & 7) << 3))];
            }
#pragma unroll
            for (int mt = 0; mt < 4; ++mt)
#pragma unroll
                for (int nt = 0; nt < 4; ++nt)
                    acc[mt][nt] = MFMA_F16(af[mt], bfr[nt], acc[mt][nt], 0, 0, 0);
        }
    };

    stage(0, 0);
    __syncthreads();              // implicit vmcnt(0): tile 0 resident
    for (int k0 = 0; k0 < HID; k0 += 128) {
        stage(1, k0 + 64);        // prefetch while computing buf 0
        compute(0);
        __syncthreads();          // drain lands after ~700cyc of compute
        if (k0 + 128 < HID) stage(0, k0 + 128);
        compute(1);
        __syncthreads();
    }

    GemmCtx c{m0, n0, wm, wn, quad, l16};
    epi(acc, c);
}

template <int MODE, typename TOut>
__global__ __launch_bounds__(256) void gemm16(
    const half_t* __restrict__ A, const half_t* __restrict__ W,
    const float* __restrict__ bias, TOut* __restrict__ Out)
{
    __shared__ half_t As[2 * 128 * 64];
    __shared__ half_t Bs[2 * 128 * 64];
    gemm_body(A, W, As, Bs,
        [&](const floatx4 (&acc)[4][4], const GemmCtx& c) {
            epilogue_store<MODE, TOut>(acc, bias, Out, c.m0, c.n0,
                                       c.wm, c.wn, c.quad, c.l16);
        });
}

// ---------------------------------------------------------------------------
// Legacy GEMM (fp32 A/W, reg-staged cvt) — fallback if ws too small for the
// fp16 pre-convert path.
// ---------------------------------------------------------------------------
template <int MODE, typename TA, typename TOut>
__global__ __launch_bounds__(256) void gemm_bt(
    const TA* __restrict__ A, const float* __restrict__ W,
    const float* __restrict__ bias, TOut* __restrict__ Out)
{
    __shared__ half_t As[128][40];
    __shared__ half_t Bs[128][40];

    const int tid  = threadIdx.x;
    const int m0   = blockIdx.y * 128;
    const int n0   = blockIdx.x * 128;
    const int wave = tid >> 6;
    const int lane = tid & 63;
    const int quad = lane >> 4;
    const int l16  = lane & 15;
    const int wm   = (wave >> 1) * 64;
    const int wn   = (wave & 1) * 64;
    const int trow = tid >> 1;
    const int tcol = (tid & 1) * 16;

    const TA*    aptr = A + (size_t)(m0 + trow) * HID + tcol;
    const float* bptr = W + (size_t)(n0 + trow) * HID + tcol;

    floatx4 acc[4][4];
    const floatx4 zero4 = {0.f, 0.f, 0.f, 0.f};
#pragma unroll
    for (int mt = 0; mt < 4; ++mt)
#pragma unroll
        for (int nt = 0; nt < 4; ++nt) acc[mt][nt] = zero4;

    for (int k0 = 0; k0 < HID; k0 += 32) {
        halfx8 av0 = load8h(aptr);
        halfx8 av1 = load8h(aptr + 8);
        halfx8 bv0 = load8h(bptr);
        halfx8 bv1 = load8h(bptr + 8);
        aptr += 32;
        bptr += 32;

        __syncthreads();
        *(halfx8*)&As[trow][tcol]     = av0;
        *(halfx8*)&As[trow][tcol + 8] = av1;
        *(halfx8*)&Bs[trow][tcol]     = bv0;
        *(halfx8*)&Bs[trow][tcol + 8] = bv1;
        __syncthreads();

        halfx8 af[4], bfr[4];
#pragma unroll
        for (int t = 0; t < 4; ++t) {
            af[t]  = *(const halfx8*)&As[wm + t * 16 + l16][quad * 8];
            bfr[t] = *(const halfx8*)&Bs[wn + t * 16 + l16][quad * 8];
        }
#pragma unroll
        for (int mt = 0; mt < 4; ++mt)
#pragma unroll
            for (int nt = 0; nt < 4; ++nt)
                acc[mt][nt] = MFMA_F16(af[mt], bfr[nt], acc[mt][nt], 0, 0, 0);
    }

    epilogue_store<MODE, TOut>(acc, bias, Out, m0, n0, wm, wn, quad, l16);
}

// ---------------------------------------------------------------------------
// fp32 -> fp16 conversion kernels (memory-bound, vectorized 8/thread).
// cvt_act3: one launch converts q, k, v (blockIdx.y selects).
// ---------------------------------------------------------------------------
__global__ __launch_bounds__(256) void cvt_act3(
    const float* __restrict__ q, const float* __restrict__ k,
    const float* __restrict__ v,
    half_t* __restrict__ q16, half_t* __restrict__ k16, half_t* __restrict__ v16)
{
    const int t = blockIdx.y;
    const float* src = (t == 0) ? q : (t == 1) ? k : v;
    half_t* dst = (t == 0) ? q16 : (t == 1) ? k16 : v16;
    const size_t i = ((size_t)blockIdx.x * 256 + threadIdx.x) * 8;
    *(halfx8*)(dst + i) = load8h(src + i);
}

__global__ __launch_bounds__(256) void cvt_w4(
    const float* __restrict__ w0, const float* __restrict__ w1,
    const float* __restrict__ w2, const float* __restrict__ w3,
    half_t* __restrict__ out)
{
    const int t = blockIdx.y;
    const float* src = (t == 0) ? w0 : (t == 1) ? w1 : (t == 2) ? w2 : w3;
    const size_t i = ((size_t)blockIdx.x * 256 + threadIdx.x) * 8;
    *(halfx8*)(out + (size_t)t * NWELEM + i) = load8h(src + i);
}

// ---------------------------------------------------------------------------
// Causal flash attention, fp16, swapped-QK^T (in-register softmax), with
// R2-proven shfl-based cross-lane ops, + T13 defer-max + T14 async staging.
// UNCHANGED from R4 (proven 101 us).
// ---------------------------------------------------------------------------
__global__ __launch_bounds__(256) void attn_kernel(
    const half_t* __restrict__ Q, const half_t* __restrict__ K,
    const half_t* __restrict__ VT, half_t* __restrict__ O)
{
    __shared__ half_t Ks[64][72];      // [k][d]
    __shared__ half_t Vt[64][72];      // [d][k]

    const int bh  = blockIdx.x;                      // b*HEADS + h
    const int qt  = (gridDim.y - 1) - blockIdx.y;    // heaviest tiles first
    const int q0  = qt * 128;
    const int tid = threadIdx.x;
    const int wave = tid >> 6;
    const int lane = tid & 63;
    const int quad = lane >> 4;
    const int l16  = lane & 15;

    const half_t* Qb  = Q  + (size_t)bh * SEQ * HD;
    const half_t* Kb  = K  + (size_t)bh * SEQ * HD;
    const half_t* VTb = VT + (size_t)bh * HD * SEQ;

    // Q fragments (B-operand of swapped QK^T): B[n=q=l16][k=d=quad*8+j]
    halfx8 aq[2][2];
#pragma unroll
    for (int mt = 0; mt < 2; ++mt) {
        const half_t* p = Qb + (size_t)(q0 + wave * 32 + mt * 16 + l16) * HD + quad * 8;
        aq[mt][0] = *(const halfx8*)p;
        aq[mt][1] = *(const halfx8*)(p + 32);
    }

    const floatx4 zero4 = {0.f, 0.f, 0.f, 0.f};
    floatx4 oaccT[2][4];   // [mt][dt]: lane holds O[q=mt*16+l16][d=dt*16+quad*4+r]
    float mrow[2], lrow[2];
#pragma unroll
    for (int mt = 0; mt < 2; ++mt) {
        mrow[mt] = -3.0e38f;
        lrow[mt] = 0.f;
#pragma unroll
        for (int dt = 0; dt < 4; ++dt) oaccT[mt][dt] = zero4;
    }

    const int srow = tid >> 2;         // 0..63
    const int scol = (tid & 3) * 16;   // 0,16,32,48
    const int ktiles = 2 * qt + 2;

    union U8 { halfx8 h; uint32_t u[4]; };

    // T14 prologue: tile 0 K/V -> regs
    halfx8 nk0, nk1, nv0, nv1;
    {
        const half_t* ksrc = Kb + (size_t)srow * HD + scol;
        nk0 = *(const halfx8*)ksrc;
        nk1 = *(const halfx8*)(ksrc + 8);
        const half_t* vsrc = VTb + (size_t)srow * SEQ + scol;
        nv0 = *(const halfx8*)vsrc;
        nv1 = *(const halfx8*)(vsrc + 8);
    }

    for (int kt = 0; kt < ktiles; ++kt) {
        const int k0 = kt * 64;
        __syncthreads();  // prior iter's Ks/Vt reads done
        *(halfx8*)&Ks[srow][scol]     = nk0;
        *(halfx8*)&Ks[srow][scol + 8] = nk1;
        *(halfx8*)&Vt[srow][scol]     = nv0;
        *(halfx8*)&Vt[srow][scol + 8] = nv1;
        __syncthreads();

        // T14: issue next tile's global loads before this tile's compute
        if (kt + 1 < ktiles) {
            const int kn = k0 + 64;
            const half_t* ksrc = Kb + (size_t)(kn + srow) * HD + scol;
            nk0 = *(const halfx8*)ksrc;
            nk1 = *(const halfx8*)(ksrc + 8);
            const half_t* vsrc = VTb + (size_t)srow * SEQ + kn + scol;
            nv0 = *(const halfx8*)vsrc;
            nv1 = *(const halfx8*)(vsrc + 8);
        }

        // wave-uniform activity predicate (no continue: barriers stay uniform)
        const bool active = (k0 <= q0 + wave * 32 + 31);

        if (active) {
            // S^T: sacc[mt][nt] rows kv, cols q (swapped operands)
            floatx4 sacc[2][4];
#pragma unroll
            for (int mt = 0; mt < 2; ++mt)
#pragma unroll
                for (int nt = 0; nt < 4; ++nt) sacc[mt][nt] = zero4;
#pragma unroll
            for (int nt = 0; nt < 4; ++nt) {
                halfx8 bk0 = *(const halfx8*)&Ks[nt * 16 + l16][quad * 8];
                halfx8 bk1 = *(const halfx8*)&Ks[nt * 16 + l16][quad * 8 + 32];
#pragma unroll
                for (int mt = 0; mt < 2; ++mt) {
                    sacc[mt][nt] = MFMA_F16(bk0, aq[mt][0], sacc[mt][nt], 0, 0, 0);
                    sacc[mt][nt] = MFMA_F16(bk1, aq[mt][1], sacc[mt][nt], 0, 0, 0);
                }
            }

            if (kt >= 2 * qt) {  // diagonal region: mask kv > q
#pragma unroll
                for (int mt = 0; mt < 2; ++mt) {
                    const int qg = q0 + wave * 32 + mt * 16 + l16;
#pragma unroll
                    for (int nt = 0; nt < 4; ++nt) {
                        const int kg = k0 + nt * 16 + quad * 4;
#pragma unroll
                        for (int r = 0; r < 4; ++r)
                            if (kg + r > qg) sacc[mt][nt][r] = -1.0e30f;
                    }
                }
            }

            // in-register online softmax (per lane = per q row, 16 vals)
            uint32_t pk[2][4][2];
#pragma unroll
            for (int mt = 0; mt < 2; ++mt) {
                float mx = sacc[mt][0][0];
#pragma unroll
                for (int nt = 0; nt < 4; ++nt)
#pragma unroll
                    for (int r = 0; r < 4; ++r)
                        if (nt | r) mx = fmaxf(mx, sacc[mt][nt][r]);
                mx = fmaxf(mx, __shfl_xor(mx, 16));
                mx = fmaxf(mx, __shfl_xor(mx, 32));

                // T13 defer-max: skip rescale while tile max lags running
                // max by <= 8 (P <= e^8 = 2981 fits fp16; fp32 accum).
                if (!__all(mx <= mrow[mt] + 8.f)) {
                    const float mnew  = fmaxf(mrow[mt], mx);
                    const float alpha = __expf(mrow[mt] - mnew);
                    mrow[mt] = mnew;
                    lrow[mt] *= alpha;
#pragma unroll
                    for (int dt = 0; dt < 4; ++dt) oaccT[mt][dt] *= alpha;
                }

                float rsum = 0.f;
#pragma unroll
                for (int nt = 0; nt < 4; ++nt)
#pragma unroll
                    for (int r = 0; r < 4; ++r) {
                        const float p = __expf(sacc[mt][nt][r] - mrow[mt]);
                        sacc[mt][nt][r] = p;
                        rsum += p;
                    }
#pragma unroll
                for (int nt = 0; nt < 4; ++nt) {
                    pk[mt][nt][0] = pack2h(sacc[mt][nt][0], sacc[mt][nt][1]);
                    pk[mt][nt][1] = pack2h(sacc[mt][nt][2], sacc[mt][nt][3]);
                }
                rsum += __shfl_xor(rsum, 16);
                rsum += __shfl_xor(rsum, 32);
                lrow[mt] += rsum;
            }

            // redistribute P^T C-layout -> PV B-frag [n=q=l16][k=kv=quad*8+j].
            // (R2-proven shfl mapping.)
            U8 pb[2][2];  // [mt][s2]
#pragma unroll
            for (int mt = 0; mt < 2; ++mt)
#pragma unroll
                for (int s2 = 0; s2 < 2; ++s2)
#pragma unroll
                    for (int w = 0; w < 4; ++w) {
                        const int src = l16 + ((quad & 1) << 5) + ((w >> 1) << 4);
                        const uint32_t lo =
                            (uint32_t)__shfl((int)pk[mt][2 * s2][w & 1], src, 64);
                        const uint32_t hi =
                            (uint32_t)__shfl((int)pk[mt][2 * s2 + 1][w & 1], src, 64);
                        pb[mt][s2].u[w] = (quad >> 1) ? hi : lo;
                    }

            // PV: O^T = MFMA(A=V^T frag, B=P frag)
#pragma unroll
            for (int s2 = 0; s2 < 2; ++s2)
#pragma unroll
                for (int dt = 0; dt < 4; ++dt) {
                    halfx8 bv = *(const halfx8*)&Vt[dt * 16 + l16][s2 * 32 + quad * 8];
                    oaccT[0][dt] = MFMA_F16(bv, pb[0][s2].h, oaccT[0][dt], 0, 0, 0);
                    oaccT[1][dt] = MFMA_F16(bv, pb[1][s2].h, oaccT[1][dt], 0, 0, 0);
                }
        }
    }

    // epilogue: O^T fragment -> Ob[b][q][h*64+d], halfx4 along d
    const int b = bh >> 4, h = bh & (HEADS - 1);
#pragma unroll
    for (int mt = 0; mt < 2; ++mt) {
        const int q = q0 + wave * 32 + mt * 16 + l16;
#pragma unroll
        for (int dt = 0; dt < 4; ++dt) {
            halfx4 st;
#pragma unroll
            for (int r = 0; r < 4; ++r)
                st[r] = (half_t)(oaccT[mt][dt][r] / lrow[mt]);
            *(halfx4*)(O + (size_t)(b * SEQ + q) * HID +
                       h * HD + dt * 16 + quad * 4) = st;
        }
    }
}

// ---------------------------------------------------------------------------
extern "C" void kernel_launch(void* const* d_in, const int* in_sizes, int n_in,
                              void* d_out, int out_size, void* d_ws, size_t ws_size,
                              hipStream_t stream)
{
    const float* query = (const float*)d_in[0];
    const float* key   = (const float*)d_in[1];
    const float* value = (const float*)d_in[2];
    const float* Wq    = (const float*)d_in[3];
    const float* bq    = (const float*)d_in[4];
    const float* Wk    = (const float*)d_in[5];
    const float* bk    = (const float*)d_in[6];
    const float* Wv    = (const float*)d_in[7];
    const float* bv    = (const float*)d_in[8];
    const float* Wo    = (const float*)d_in[9];
    const float* bo    = (const float*)d_in[10];
    float* out = (float*)d_out;

    // workspace (fp16): Qp, Kp [B][H][S][D]; VpT [B][H][D][S]; Ob [M][HID];
    // W16 [4][HID][HID] = 75.5 MB (proven R1-R5).  The three fp16 activations
    // are live together (single cvt launch): q16/k16 in d_out used as scratch
    // (2*NE*2B == out_size; d_out dead until gemm_final rewrites all of it,
    // proven R5), v16 in the Ob slot (dead until attn).  GEMMs run SERIALLY
    // (R5 lesson: concurrent QKV thrashes per-XCD L2 with 3 Ws).
    const size_t NE = (size_t)MTOT * HID;
    half_t* Qp  = (half_t*)d_ws;
    half_t* Kp  = Qp  + NE;
    half_t* VpT = Kp  + NE;
    half_t* Ob  = VpT + NE;
    half_t* W16 = Ob  + NE;
    const size_t need = (4 * NE + 4 * (size_t)NWELEM) * sizeof(half_t);

    dim3 gg(HID / 128, MTOT / 128);     // (8, 64)
    dim3 ga(BATCH * HEADS, SEQ / 128);  // (64, 16)

    if (ws_size >= need && (size_t)out_size >= 2 * NE * sizeof(half_t)) {
        half_t* q16 = (half_t*)out;       // d_out scratch
        half_t* k16 = q16 + NE;
        half_t* v16 = Ob;                 // Ob slot scratch
        const unsigned actBlocks = (unsigned)(NE / 2048);      // 4096
        const unsigned wBlocks   = (unsigned)(NWELEM / 2048);  // 512

        cvt_w4<<<dim3(wBlocks, 4), 256, 0, stream>>>(Wq, Wk, Wv, Wo, W16);
        cvt_act3<<<dim3(actBlocks, 3), 256, 0, stream>>>(
            query, key, value, q16, k16, v16);

        gemm16<0, half_t><<<gg, 256, 0, stream>>>(q16, W16, bq, Qp);
        gemm16<0, half_t><<<gg, 256, 0, stream>>>(k16, W16 + NWELEM, bk, Kp);
        gemm16<2, half_t><<<gg, 256, 0, stream>>>(v16, W16 + 2 * (size_t)NWELEM, bv, VpT);

        attn_kernel<<<ga, 256, 0, stream>>>(Qp, Kp, VpT, Ob);

        gemm16<1, float><<<gg, 256, 0, stream>>>(Ob, W16 + 3 * (size_t)NWELEM, bo, out);
    } else {
        // legacy fallback path
        gemm_bt<0, float, half_t><<<gg, 256, 0, stream>>>(query, Wq, bq, Qp);
        gemm_bt<0, float, half_t><<<gg, 256, 0, stream>>>(key,   Wk, bk, Kp);
        gemm_bt<2, float, half_t><<<gg, 256, 0, stream>>>(value, Wv, bv, VpT);
        attn_kernel<<<ga, 256, 0, stream>>>(Qp, Kp, VpT, Ob);
        gemm_bt<1, half_t, float><<<gg, 256, 0, stream>>>(Ob, Wo, bo, out);
    }
}

// Round 7
// 422.784 us; speedup vs baseline: 1.0294x; 1.0269x over previous
//
#include <hip/hip_runtime.h>
#include <hip/hip_fp16.h>

typedef _Float16 half_t;
typedef half_t halfx8 __attribute__((ext_vector_type(8)));
typedef half_t halfx4 __attribute__((ext_vector_type(4)));
typedef float floatx4 __attribute__((ext_vector_type(4)));

#define HID 1024
#define HEADS 16
#define HD 64
#define BATCH 4
#define SEQ 2048
#define MTOT (BATCH * SEQ) /* 8192 */
#define NWELEM (HID * HID) /* 1048576 */

#define MFMA_F16 __builtin_amdgcn_mfma_f32_16x16x32_f16

// Load 8 contiguous elements as halfx8; fp32 source converts on the fly.
__device__ inline halfx8 load8h(const half_t* p) { return *(const halfx8*)p; }
__device__ inline halfx8 load8h(const float* p) {
    floatx4 x = *(const floatx4*)p;
    floatx4 y = *(const floatx4*)(p + 4);
    halfx8 r;
    r[0] = (half_t)x[0]; r[1] = (half_t)x[1];
    r[2] = (half_t)x[2]; r[3] = (half_t)x[3];
    r[4] = (half_t)y[0]; r[5] = (half_t)y[1];
    r[6] = (half_t)y[2]; r[7] = (half_t)y[3];
    return r;
}

// pack two fp32 -> one dword of 2 fp16 (RTN, matches (half_t) cast numerics)
__device__ __forceinline__ uint32_t pack2h(float a, float b) {
    union { half_t h[2]; uint32_t u; } r;
    r.h[0] = (half_t)a; r.h[1] = (half_t)b;
    return r.u;
}

// async 16B global->LDS: LDS dest is wave-uniform base + lane*16 (m104/m173);
// global src is per-lane. size arg must be a literal (16).
__device__ __forceinline__ void gl_lds16(const half_t* g, half_t* lds) {
    __builtin_amdgcn_global_load_lds(
        (const __attribute__((address_space(1))) void*)g,
        (__attribute__((address_space(3))) void*)lds, 16, 0, 0);
}

// --- gfx950 permlane swaps (VALU cross-lane, zero DS) ----------------------
// v_permlane32_swap_b32 a,b: a[32:63] <-> b[0:31]
//   => a' = [a.lo, b.lo], b' = [a.hi, b.hi]   (16-lane rows: lo=r0r1, hi=r2r3)
// v_permlane16_swap_b32 a,b: a's odd 16-lane rows <-> b's even rows
//   => a' = [a.r0, b.r0, a.r2, b.r2], b' = [a.r1, b.r1, a.r3, b.r3]
// SAFETY (R3 post-mortem): operands MUST hold distinct values; identical
// values let the compiler alias them to one VGPR and the swap self-corrupts.
// Used ONLY for the P transpose where a,b are different MFMA results.
__device__ __forceinline__ void pl32swap(uint32_t& a, uint32_t& b) {
    asm volatile("v_permlane32_swap_b32 %0, %1" : "+v"(a), "+v"(b));
}
__device__ __forceinline__ void pl16swap(uint32_t& a, uint32_t& b) {
    asm volatile("v_permlane16_swap_b32 %0, %1" : "+v"(a), "+v"(b));
}

// ---------------------------------------------------------------------------
// Shared GEMM epilogue.  C/D layout: col = lane&15, row = quad*4 + reg
// [m89-verified].
// MODE 0: fp16 -> [B][H][S][D]   (Q, K)
// MODE 1: fp32 -> flat [M, N]    (final)
// MODE 2: fp16 -> [B][H][D][S]   (V transposed; 8B-aligned halfx4 stores)
// ---------------------------------------------------------------------------
template <int MODE, typename TOut>
__device__ __forceinline__ void epilogue_store(
    const floatx4 (&acc)[4][4], const float* __restrict__ bias,
    TOut* __restrict__ Out, int m0, int n0, int wm, int wn, int quad, int l16)
{
    float bvals[4];
#pragma unroll
    for (int nt = 0; nt < 4; ++nt)
        bvals[nt] = bias[n0 + wn + nt * 16 + l16];

#pragma unroll
    for (int mt = 0; mt < 4; ++mt) {
        const int mbase = m0 + wm + mt * 16 + quad * 4;
#pragma unroll
        for (int nt = 0; nt < 4; ++nt) {
            const int n = n0 + wn + nt * 16 + l16;
            if (MODE == 2) {
                const int b = mbase >> 11, s = mbase & (SEQ - 1);
                const int h = n >> 6, d = n & (HD - 1);
                halfx4 st;
#pragma unroll
                for (int r = 0; r < 4; ++r)
                    st[r] = (half_t)(acc[mt][nt][r] + bvals[nt]);
                *(halfx4*)((half_t*)Out +
                    ((((size_t)b * HEADS + h) * HD + d) << 11) + s) = st;
            } else {
#pragma unroll
                for (int r = 0; r < 4; ++r) {
                    const float v = acc[mt][nt][r] + bvals[nt];
                    const int mm  = mbase + r;
                    if (MODE == 0) {
                        const int b = mm >> 11, s = mm & (SEQ - 1);
                        const int h = n >> 6, d = n & (HD - 1);
                        Out[((((size_t)b * HEADS + h) * SEQ + s) << 6) + d] = (TOut)v;
                    } else {
                        Out[(size_t)mm * HID + n] = (TOut)v;
                    }
                }
            }
        }
    }
}

// ---------------------------------------------------------------------------
// Fast GEMM (fp16 A and W): Out = A @ W^T + bias.  R4-PROVEN structure:
// 128x128 tile, BK=32, 256 thr (4 waves 2x2), mfma 16x16x32 f16,
// 2-phase double-buffered LDS (2 x 128x32 per matrix = 32 KB) staged via
// global_load_lds width=16.  (R6 lesson: BK=64 scales bytes with compute —
// no amortization win — and regressed; stay at BK=32.)
// XCD swizzle: nwg=512 (%8==0); per-XCD footprint = A-panel 2MB + W 2MB =
// 4MB = one L2 (R5 lesson: concurrent Ws thrash this).
// ---------------------------------------------------------------------------
template <int MODE, typename TOut>
__global__ __launch_bounds__(256) void gemm16(
    const half_t* __restrict__ A, const half_t* __restrict__ W,
    const float* __restrict__ bias, TOut* __restrict__ Out)
{
    __shared__ half_t As[2][128 * 32];
    __shared__ half_t Bs[2][128 * 32];

    const int tid  = threadIdx.x;
    const int id   = blockIdx.y * gridDim.x + blockIdx.x;
    const int cpx  = (gridDim.x * gridDim.y) >> 3;
    const int swz  = (id & 7) * cpx + (id >> 3);
    const int m0   = (swz >> 3) * 128;          // gridDim.x == 8
    const int n0   = (swz & 7) * 128;
    const int wave = tid >> 6;
    const int lane = tid & 63;
    const int quad = lane >> 4;
    const int l16  = lane & 15;
    const int wm   = (wave >> 1) * 64;
    const int wn   = (wave & 1) * 64;

    // staging map: wave w owns chunks 2w,2w+1 (16 rows each) of A and B.
    // Lane i -> row c0*16 + (i>>2), half-col (i&3)*8 (16 B). HW writes LDS
    // at wave-uniform base + lane*16 -> layout matches linear [128][32].
    const int c0   = wave * 2;
    const int srow = c0 * 16 + (lane >> 2);
    const int scol = (lane & 3) * 8;
    const half_t* aptr0 = A + (size_t)(m0 + srow) * HID + scol;
    const half_t* aptr1 = aptr0 + (size_t)16 * HID;
    const half_t* bptr0 = W + (size_t)(n0 + srow) * HID + scol;
    const half_t* bptr1 = bptr0 + (size_t)16 * HID;

    floatx4 acc[4][4];
    const floatx4 zero4 = {0.f, 0.f, 0.f, 0.f};
#pragma unroll
    for (int mt = 0; mt < 4; ++mt)
#pragma unroll
        for (int nt = 0; nt < 4; ++nt) acc[mt][nt] = zero4;

    auto stage = [&](int buf, int k0) {
        gl_lds16(aptr0 + k0, &As[buf][c0 * 512]);
        gl_lds16(aptr1 + k0, &As[buf][c0 * 512 + 512]);
        gl_lds16(bptr0 + k0, &Bs[buf][c0 * 512]);
        gl_lds16(bptr1 + k0, &Bs[buf][c0 * 512 + 512]);
    };
    auto compute = [&](int buf) {
        halfx8 af[4], bfr[4];
#pragma unroll
        for (int t = 0; t < 4; ++t) {
            af[t]  = *(const halfx8*)&As[buf][(wm + t * 16 + l16) * 32 + quad * 8];
            bfr[t] = *(const halfx8*)&Bs[buf][(wn + t * 16 + l16) * 32 + quad * 8];
        }
#pragma unroll
        for (int mt = 0; mt < 4; ++mt)
#pragma unroll
            for (int nt = 0; nt < 4; ++nt)
                acc[mt][nt] = MFMA_F16(af[mt], bfr[nt], acc[mt][nt], 0, 0, 0);
    };

    stage(0, 0);
    __syncthreads();              // implicit vmcnt(0): tile 0 resident
    for (int k0 = 0; k0 < HID; k0 += 64) {
        stage(1, k0 + 32);        // prefetch while computing buf 0
        compute(0);
        __syncthreads();          // drain: prefetch landed; buf0 reads done
        if (k0 + 64 < HID) stage(0, k0 + 64);
        compute(1);
        __syncthreads();
    }

    epilogue_store<MODE, TOut>(acc, bias, Out, m0, n0, wm, wn, quad, l16);
}

// ---------------------------------------------------------------------------
// Legacy GEMM (fp32 A/W, reg-staged cvt) — fallback if ws too small for the
// fp16 pre-convert path.
// ---------------------------------------------------------------------------
template <int MODE, typename TA, typename TOut>
__global__ __launch_bounds__(256) void gemm_bt(
    const TA* __restrict__ A, const float* __restrict__ W,
    const float* __restrict__ bias, TOut* __restrict__ Out)
{
    __shared__ half_t As[128][40];
    __shared__ half_t Bs[128][40];

    const int tid  = threadIdx.x;
    const int m0   = blockIdx.y * 128;
    const int n0   = blockIdx.x * 128;
    const int wave = tid >> 6;
    const int lane = tid & 63;
    const int quad = lane >> 4;
    const int l16  = lane & 15;
    const int wm   = (wave >> 1) * 64;
    const int wn   = (wave & 1) * 64;
    const int trow = tid >> 1;
    const int tcol = (tid & 1) * 16;

    const TA*    aptr = A + (size_t)(m0 + trow) * HID + tcol;
    const float* bptr = W + (size_t)(n0 + trow) * HID + tcol;

    floatx4 acc[4][4];
    const floatx4 zero4 = {0.f, 0.f, 0.f, 0.f};
#pragma unroll
    for (int mt = 0; mt < 4; ++mt)
#pragma unroll
        for (int nt = 0; nt < 4; ++nt) acc[mt][nt] = zero4;

    for (int k0 = 0; k0 < HID; k0 += 32) {
        halfx8 av0 = load8h(aptr);
        halfx8 av1 = load8h(aptr + 8);
        halfx8 bv0 = load8h(bptr);
        halfx8 bv1 = load8h(bptr + 8);
        aptr += 32;
        bptr += 32;

        __syncthreads();
        *(halfx8*)&As[trow][tcol]     = av0;
        *(halfx8*)&As[trow][tcol + 8] = av1;
        *(halfx8*)&Bs[trow][tcol]     = bv0;
        *(halfx8*)&Bs[trow][tcol + 8] = bv1;
        __syncthreads();

        halfx8 af[4], bfr[4];
#pragma unroll
        for (int t = 0; t < 4; ++t) {
            af[t]  = *(const halfx8*)&As[wm + t * 16 + l16][quad * 8];
            bfr[t] = *(const halfx8*)&Bs[wn + t * 16 + l16][quad * 8];
        }
#pragma unroll
        for (int mt = 0; mt < 4; ++mt)
#pragma unroll
            for (int nt = 0; nt < 4; ++nt)
                acc[mt][nt] = MFMA_F16(af[mt], bfr[nt], acc[mt][nt], 0, 0, 0);
    }

    epilogue_store<MODE, TOut>(acc, bias, Out, m0, n0, wm, wn, quad, l16);
}

// ---------------------------------------------------------------------------
// fp32 -> fp16 conversion kernels (memory-bound, vectorized 8/thread).
// cvt_act3: one launch converts q, k, v (blockIdx.y selects).
// ---------------------------------------------------------------------------
__global__ __launch_bounds__(256) void cvt_act3(
    const float* __restrict__ q, const float* __restrict__ k,
    const float* __restrict__ v,
    half_t* __restrict__ q16, half_t* __restrict__ k16, half_t* __restrict__ v16)
{
    const int t = blockIdx.y;
    const float* src = (t == 0) ? q : (t == 1) ? k : v;
    half_t* dst = (t == 0) ? q16 : (t == 1) ? k16 : v16;
    const size_t i = ((size_t)blockIdx.x * 256 + threadIdx.x) * 8;
    *(halfx8*)(dst + i) = load8h(src + i);
}

__global__ __launch_bounds__(256) void cvt_w4(
    const float* __restrict__ w0, const float* __restrict__ w1,
    const float* __restrict__ w2, const float* __restrict__ w3,
    half_t* __restrict__ out)
{
    const int t = blockIdx.y;
    const float* src = (t == 0) ? w0 : (t == 1) ? w1 : (t == 2) ? w2 : w3;
    const size_t i = ((size_t)blockIdx.x * 256 + threadIdx.x) * 8;
    *(halfx8*)(out + (size_t)t * NWELEM + i) = load8h(src + i);
}

// ---------------------------------------------------------------------------
// Causal flash attention, fp16, swapped-QK^T (in-register softmax).
// R4-proven base + PERMLANE TRANSPOSE for the P redistribution (replaces
// 32 ds_bpermute + 32 cndmask with 16 VALU permlane swaps; operands are
// distinct MFMA results so no register-alias hazard — R3 post-mortem).
// Softmax max/sum reductions stay on proven __shfl_xor.
// T13 defer-max + T14 async K/V staging unchanged.
// ---------------------------------------------------------------------------
__global__ __launch_bounds__(256) void attn_kernel(
    const half_t* __restrict__ Q, const half_t* __restrict__ K,
    const half_t* __restrict__ VT, half_t* __restrict__ O)
{
    __shared__ half_t Ks[64][72];      // [k][d]
    __shared__ half_t Vt[64][72];      // [d][k]

    const int bh  = blockIdx.x;                      // b*HEADS + h
    const int qt  = (gridDim.y - 1) - blockIdx.y;    // heaviest tiles first
    const int q0  = qt * 128;
    const int tid = threadIdx.x;
    const int wave = tid >> 6;
    const int lane = tid & 63;
    const int quad = lane >> 4;
    const int l16  = lane & 15;

    const half_t* Qb  = Q  + (size_t)bh * SEQ * HD;
    const half_t* Kb  = K  + (size_t)bh * SEQ * HD;
    const half_t* VTb = VT + (size_t)bh * HD * SEQ;

    // Q fragments (B-operand of swapped QK^T): B[n=q=l16][k=d=quad*8+j]
    halfx8 aq[2][2];
#pragma unroll
    for (int mt = 0; mt < 2; ++mt) {
        const half_t* p = Qb + (size_t)(q0 + wave * 32 + mt * 16 + l16) * HD + quad * 8;
        aq[mt][0] = *(const halfx8*)p;
        aq[mt][1] = *(const halfx8*)(p + 32);
    }

    const floatx4 zero4 = {0.f, 0.f, 0.f, 0.f};
    floatx4 oaccT[2][4];   // [mt][dt]: lane holds O[q=mt*16+l16][d=dt*16+quad*4+r]
    float mrow[2], lrow[2];
#pragma unroll
    for (int mt = 0; mt < 2; ++mt) {
        mrow[mt] = -3.0e38f;
        lrow[mt] = 0.f;
#pragma unroll
        for (int dt = 0; dt < 4; ++dt) oaccT[mt][dt] = zero4;
    }

    const int srow = tid >> 2;         // 0..63
    const int scol = (tid & 3) * 16;   // 0,16,32,48
    const int ktiles = 2 * qt + 2;

    union U8 { halfx8 h; uint32_t u[4]; };

    // T14 prologue: tile 0 K/V -> regs
    halfx8 nk0, nk1, nv0, nv1;
    {
        const half_t* ksrc = Kb + (size_t)srow * HD + scol;
        nk0 = *(const halfx8*)ksrc;
        nk1 = *(const halfx8*)(ksrc + 8);
        const half_t* vsrc = VTb + (size_t)srow * SEQ + scol;
        nv0 = *(const halfx8*)vsrc;
        nv1 = *(const halfx8*)(vsrc + 8);
    }

    for (int kt = 0; kt < ktiles; ++kt) {
        const int k0 = kt * 64;
        __syncthreads();  // prior iter's Ks/Vt reads done
        *(halfx8*)&Ks[srow][scol]     = nk0;
        *(halfx8*)&Ks[srow][scol + 8] = nk1;
        *(halfx8*)&Vt[srow][scol]     = nv0;
        *(halfx8*)&Vt[srow][scol + 8] = nv1;
        __syncthreads();

        // T14: issue next tile's global loads before this tile's compute
        if (kt + 1 < ktiles) {
            const int kn = k0 + 64;
            const half_t* ksrc = Kb + (size_t)(kn + srow) * HD + scol;
            nk0 = *(const halfx8*)ksrc;
            nk1 = *(const halfx8*)(ksrc + 8);
            const half_t* vsrc = VTb + (size_t)srow * SEQ + kn + scol;
            nv0 = *(const halfx8*)vsrc;
            nv1 = *(const halfx8*)(vsrc + 8);
        }

        // wave-uniform activity predicate (no continue: barriers stay uniform)
        const bool active = (k0 <= q0 + wave * 32 + 31);

        if (active) {
            // S^T: sacc[mt][nt] rows kv, cols q (swapped operands)
            floatx4 sacc[2][4];
#pragma unroll
            for (int mt = 0; mt < 2; ++mt)
#pragma unroll
                for (int nt = 0; nt < 4; ++nt) sacc[mt][nt] = zero4;
#pragma unroll
            for (int nt = 0; nt < 4; ++nt) {
                halfx8 bk0 = *(const halfx8*)&Ks[nt * 16 + l16][quad * 8];
                halfx8 bk1 = *(const halfx8*)&Ks[nt * 16 + l16][quad * 8 + 32];
#pragma unroll
                for (int mt = 0; mt < 2; ++mt) {
                    sacc[mt][nt] = MFMA_F16(bk0, aq[mt][0], sacc[mt][nt], 0, 0, 0);
                    sacc[mt][nt] = MFMA_F16(bk1, aq[mt][1], sacc[mt][nt], 0, 0, 0);
                }
            }

            if (kt >= 2 * qt) {  // diagonal region: mask kv > q
#pragma unroll
                for (int mt = 0; mt < 2; ++mt) {
                    const int qg = q0 + wave * 32 + mt * 16 + l16;
#pragma unroll
                    for (int nt = 0; nt < 4; ++nt) {
                        const int kg = k0 + nt * 16 + quad * 4;
#pragma unroll
                        for (int r = 0; r < 4; ++r)
                            if (kg + r > qg) sacc[mt][nt][r] = -1.0e30f;
                    }
                }
            }

            // in-register online softmax (per lane = per q row, 16 vals)
            uint32_t pk[2][4][2];
#pragma unroll
            for (int mt = 0; mt < 2; ++mt) {
                float mx = sacc[mt][0][0];
#pragma unroll
                for (int nt = 0; nt < 4; ++nt)
#pragma unroll
                    for (int r = 0; r < 4; ++r)
                        if (nt | r) mx = fmaxf(mx, sacc[mt][nt][r]);
                mx = fmaxf(mx, __shfl_xor(mx, 16));
                mx = fmaxf(mx, __shfl_xor(mx, 32));

                // T13 defer-max: skip rescale while tile max lags running
                // max by <= 8 (P <= e^8 = 2981 fits fp16; fp32 accum).
                if (!__all(mx <= mrow[mt] + 8.f)) {
                    const float mnew  = fmaxf(mrow[mt], mx);
                    const float alpha = __expf(mrow[mt] - mnew);
                    mrow[mt] = mnew;
                    lrow[mt] *= alpha;
#pragma unroll
                    for (int dt = 0; dt < 4; ++dt) oaccT[mt][dt] *= alpha;
                }

                float rsum = 0.f;
#pragma unroll
                for (int nt = 0; nt < 4; ++nt)
#pragma unroll
                    for (int r = 0; r < 4; ++r) {
                        const float p = __expf(sacc[mt][nt][r] - mrow[mt]);
                        sacc[mt][nt][r] = p;
                        rsum += p;
                    }
#pragma unroll
                for (int nt = 0; nt < 4; ++nt) {
                    pk[mt][nt][0] = pack2h(sacc[mt][nt][0], sacc[mt][nt][1]);
                    pk[mt][nt][1] = pack2h(sacc[mt][nt][2], sacc[mt][nt][3]);
                }
                rsum += __shfl_xor(rsum, 16);
                rsum += __shfl_xor(rsum, 32);
                lrow[mt] += rsum;
            }

            // quad-transpose P^T -> PV B-frag [n=q=l16][k=kv=quad*8+j] via
            // permlane (pure VALU).  Derivation re-verified vs the R2-proven
            // shfl mapping:
            //   A = pk[2s2][h]   (rows r0..r3 = source quads 0..3)
            //   B = pk[2s2+1][h]
            //   pl32swap: A'=[A.r0,A.r1,B.r0,B.r1], B'=[A.r2,A.r3,B.r2,B.r3]
            //   pl16swap: A''=[A.r0,A.r2,B.r0,B.r2], B''=[A.r1,A.r3,B.r1,B.r3]
            //   u[h] = A'' (src quads 0/2), u[2+h] = B'' (src quads 1/3)
            // == target {reg nt = 2s2+(quad>>1), src lane l16+16*(2(quad&1)+(w>>1))}.
            U8 pb[2][2];  // [mt][s2]
#pragma unroll
            for (int mt = 0; mt < 2; ++mt)
#pragma unroll
                for (int s2 = 0; s2 < 2; ++s2)
#pragma unroll
                    for (int h = 0; h < 2; ++h) {
                        uint32_t a = pk[mt][2 * s2][h];
                        uint32_t b = pk[mt][2 * s2 + 1][h];
                        pl32swap(a, b);
                        pl16swap(a, b);
                        pb[mt][s2].u[h]     = a;
                        pb[mt][s2].u[2 + h] = b;
                    }

            // PV: O^T = MFMA(A=V^T frag, B=P frag)
#pragma unroll
            for (int s2 = 0; s2 < 2; ++s2)
#pragma unroll
                for (int dt = 0; dt < 4; ++dt) {
                    halfx8 bv = *(const halfx8*)&Vt[dt * 16 + l16][s2 * 32 + quad * 8];
                    oaccT[0][dt] = MFMA_F16(bv, pb[0][s2].h, oaccT[0][dt], 0, 0, 0);
                    oaccT[1][dt] = MFMA_F16(bv, pb[1][s2].h, oaccT[1][dt], 0, 0, 0);
                }
        }
    }

    // epilogue: O^T fragment -> Ob[b][q][h*64+d], halfx4 along d
    const int b = bh >> 4, h = bh & (HEADS - 1);
#pragma unroll
    for (int mt = 0; mt < 2; ++mt) {
        const int q = q0 + wave * 32 + mt * 16 + l16;
#pragma unroll
        for (int dt = 0; dt < 4; ++dt) {
            halfx4 st;
#pragma unroll
            for (int r = 0; r < 4; ++r)
                st[r] = (half_t)(oaccT[mt][dt][r] / lrow[mt]);
            *(halfx4*)(O + (size_t)(b * SEQ + q) * HID +
                       h * HD + dt * 16 + quad * 4) = st;
        }
    }
}

// ---------------------------------------------------------------------------
extern "C" void kernel_launch(void* const* d_in, const int* in_sizes, int n_in,
                              void* d_out, int out_size, void* d_ws, size_t ws_size,
                              hipStream_t stream)
{
    const float* query = (const float*)d_in[0];
    const float* key   = (const float*)d_in[1];
    const float* value = (const float*)d_in[2];
    const float* Wq    = (const float*)d_in[3];
    const float* bq    = (const float*)d_in[4];
    const float* Wk    = (const float*)d_in[5];
    const float* bk    = (const float*)d_in[6];
    const float* Wv    = (const float*)d_in[7];
    const float* bv    = (const float*)d_in[8];
    const float* Wo    = (const float*)d_in[9];
    const float* bo    = (const float*)d_in[10];
    float* out = (float*)d_out;

    // workspace (fp16): Qp, Kp [B][H][S][D]; VpT [B][H][D][S]; Ob [M][HID];
    // W16 [4][HID][HID] = 75.5 MB (proven R1-R6).  Activations live together
    // (single cvt launch): q16/k16 in d_out scratch (2*NE*2B == out_size;
    // d_out dead until gemm_final rewrites all of it — proven R5/R6), v16 in
    // the Ob slot (dead until attn).  GEMMs run SERIALLY (R5 L2 lesson).
    const size_t NE = (size_t)MTOT * HID;
    half_t* Qp  = (half_t*)d_ws;
    half_t* Kp  = Qp  + NE;
    half_t* VpT = Kp  + NE;
    half_t* Ob  = VpT + NE;
    half_t* W16 = Ob  + NE;
    const size_t need = (4 * NE + 4 * (size_t)NWELEM) * sizeof(half_t);

    dim3 gg(HID / 128, MTOT / 128);     // (8, 64)
    dim3 ga(BATCH * HEADS, SEQ / 128);  // (64, 16)

    if (ws_size >= need && (size_t)out_size >= 2 * NE * sizeof(half_t)) {
        half_t* q16 = (half_t*)out;       // d_out scratch
        half_t* k16 = q16 + NE;
        half_t* v16 = Ob;                 // Ob slot scratch
        const unsigned actBlocks = (unsigned)(NE / 2048);      // 4096
        const unsigned wBlocks   = (unsigned)(NWELEM / 2048);  // 512

        cvt_w4<<<dim3(wBlocks, 4), 256, 0, stream>>>(Wq, Wk, Wv, Wo, W16);
        cvt_act3<<<dim3(actBlocks, 3), 256, 0, stream>>>(
            query, key, value, q16, k16, v16);

        gemm16<0, half_t><<<gg, 256, 0, stream>>>(q16, W16, bq, Qp);
        gemm16<0, half_t><<<gg, 256, 0, stream>>>(k16, W16 + NWELEM, bk, Kp);
        gemm16<2, half_t><<<gg, 256, 0, stream>>>(v16, W16 + 2 * (size_t)NWELEM, bv, VpT);

        attn_kernel<<<ga, 256, 0, stream>>>(Qp, Kp, VpT, Ob);

        gemm16<1, float><<<gg, 256, 0, stream>>>(Ob, W16 + 3 * (size_t)NWELEM, bo, out);
    } else {
        // legacy fallback path
        gemm_bt<0, float, half_t><<<gg, 256, 0, stream>>>(query, Wq, bq, Qp);
        gemm_bt<0, float, half_t><<<gg, 256, 0, stream>>>(key,   Wk, bk, Kp);
        gemm_bt<2, float, half_t><<<gg, 256, 0, stream>>>(value, Wv, bv, VpT);
        attn_kernel<<<ga, 256, 0, stream>>>(Qp, Kp, VpT, Ob);
        gemm_bt<1, half_t, float><<<gg, 256, 0, stream>>>(Ob, Wo, bo, out);
    }
}

// Round 8
// 419.685 us; speedup vs baseline: 1.0370x; 1.0074x over previous
//
#include <hip/hip_runtime.h>
#include <hip/hip_fp16.h>

typedef _Float16 half_t;
typedef half_t halfx8 __attribute__((ext_vector_type(8)));
typedef half_t halfx4 __attribute__((ext_vector_type(4)));
typedef float floatx4 __attribute__((ext_vector_type(4)));

#define HID 1024
#define HEADS 16
#define HD 64
#define BATCH 4
#define SEQ 2048
#define MTOT (BATCH * SEQ) /* 8192 */
#define NWELEM (HID * HID) /* 1048576 */

#define MFMA_F16 __builtin_amdgcn_mfma_f32_16x16x32_f16

// counted waits + raw barrier (T4): loads stay in flight across barriers.
#define VM_WAIT(n) asm volatile("s_waitcnt vmcnt(" #n ")" ::: "memory")
#define BARRIER()  asm volatile("s_barrier" ::: "memory")

// Load 8 contiguous elements as halfx8; fp32 source converts on the fly.
__device__ inline halfx8 load8h(const half_t* p) { return *(const halfx8*)p; }
__device__ inline halfx8 load8h(const float* p) {
    floatx4 x = *(const floatx4*)p;
    floatx4 y = *(const floatx4*)(p + 4);
    halfx8 r;
    r[0] = (half_t)x[0]; r[1] = (half_t)x[1];
    r[2] = (half_t)x[2]; r[3] = (half_t)x[3];
    r[4] = (half_t)y[0]; r[5] = (half_t)y[1];
    r[6] = (half_t)y[2]; r[7] = (half_t)y[3];
    return r;
}

// pack two fp32 -> one dword of 2 fp16 (RTN, matches (half_t) cast numerics)
__device__ __forceinline__ uint32_t pack2h(float a, float b) {
    union { half_t h[2]; uint32_t u; } r;
    r.h[0] = (half_t)a; r.h[1] = (half_t)b;
    return r.u;
}

// async 16B global->LDS: LDS dest is wave-uniform base + lane*16 (m104/m173);
// global src is per-lane. size arg must be a literal (16).
__device__ __forceinline__ void gl_lds16(const half_t* g, half_t* lds) {
    __builtin_amdgcn_global_load_lds(
        (const __attribute__((address_space(1))) void*)g,
        (__attribute__((address_space(3))) void*)lds, 16, 0, 0);
}

// --- gfx950 permlane swaps (VALU cross-lane, zero DS) ----------------------
// v_permlane32_swap_b32 a,b: a[32:63] <-> b[0:31]
//   => a' = [a.lo, b.lo], b' = [a.hi, b.hi]   (16-lane rows: lo=r0r1, hi=r2r3)
// v_permlane16_swap_b32 a,b: a's odd 16-lane rows <-> b's even rows
//   => a' = [a.r0, b.r0, a.r2, b.r2], b' = [a.r1, b.r1, a.r3, b.r3]
// Semantics HW-validated by R7's passing composite transpose.
// SAFETY (R3 post-mortem): operands MUST occupy distinct VGPRs; identical
// SSA values get CSE'd into one register and the swap self-corrupts.  For
// self-reductions we force materialization with an explicit v_mov asm
// (input stays live afterward -> compiler must use a second register).
__device__ __forceinline__ void pl32swap(uint32_t& a, uint32_t& b) {
    asm volatile("v_permlane32_swap_b32 %0, %1" : "+v"(a), "+v"(b));
}
__device__ __forceinline__ void pl16swap(uint32_t& a, uint32_t& b) {
    asm volatile("v_permlane16_swap_b32 %0, %1" : "+v"(a), "+v"(b));
}
// cross-quad max/sum (lanes sharing l16); result in every lane.  Pure VALU.
__device__ __forceinline__ float quad_max(float x) {
    uint32_t a = __builtin_bit_cast(uint32_t, x), b;
    asm volatile("v_mov_b32 %0, %1" : "=v"(b) : "v"(a));
    pl16swap(a, b);   // a=[r0,r0,r2,r2], b=[r1,r1,r3,r3]
    float m = fmaxf(__builtin_bit_cast(float, a), __builtin_bit_cast(float, b));
    uint32_t c = __builtin_bit_cast(uint32_t, m), d;
    asm volatile("v_mov_b32 %0, %1" : "=v"(d) : "v"(c));
    pl32swap(c, d);   // c=[lo,lo], d=[hi,hi]
    return fmaxf(__builtin_bit_cast(float, c), __builtin_bit_cast(float, d));
}
__device__ __forceinline__ float quad_sum(float x) {
    uint32_t a = __builtin_bit_cast(uint32_t, x), b;
    asm volatile("v_mov_b32 %0, %1" : "=v"(b) : "v"(a));
    pl16swap(a, b);
    float s = __builtin_bit_cast(float, a) + __builtin_bit_cast(float, b);
    uint32_t c = __builtin_bit_cast(uint32_t, s), d;
    asm volatile("v_mov_b32 %0, %1" : "=v"(d) : "v"(c));
    pl32swap(c, d);
    return __builtin_bit_cast(float, c) + __builtin_bit_cast(float, d);
}

// ---------------------------------------------------------------------------
// Shared GEMM epilogue.  C/D layout: col = lane&15, row = quad*4 + reg
// [m89-verified].
// MODE 0: fp16 -> [B][H][S][D]   (Q, K)
// MODE 1: fp32 -> flat [M, N]    (final)
// MODE 2: fp16 -> [B][H][D][S]   (V transposed; 8B-aligned halfx4 stores)
// ---------------------------------------------------------------------------
template <int MODE, typename TOut>
__device__ __forceinline__ void epilogue_store(
    const floatx4 (&acc)[4][4], const float* __restrict__ bias,
    TOut* __restrict__ Out, int m0, int n0, int wm, int wn, int quad, int l16)
{
    float bvals[4];
#pragma unroll
    for (int nt = 0; nt < 4; ++nt)
        bvals[nt] = bias[n0 + wn + nt * 16 + l16];

#pragma unroll
    for (int mt = 0; mt < 4; ++mt) {
        const int mbase = m0 + wm + mt * 16 + quad * 4;
#pragma unroll
        for (int nt = 0; nt < 4; ++nt) {
            const int n = n0 + wn + nt * 16 + l16;
            if (MODE == 2) {
                const int b = mbase >> 11, s = mbase & (SEQ - 1);
                const int h = n >> 6, d = n & (HD - 1);
                halfx4 st;
#pragma unroll
                for (int r = 0; r < 4; ++r)
                    st[r] = (half_t)(acc[mt][nt][r] + bvals[nt]);
                *(halfx4*)((half_t*)Out +
                    ((((size_t)b * HEADS + h) * HD + d) << 11) + s) = st;
            } else {
#pragma unroll
                for (int r = 0; r < 4; ++r) {
                    const float v = acc[mt][nt][r] + bvals[nt];
                    const int mm  = mbase + r;
                    if (MODE == 0) {
                        const int b = mm >> 11, s = mm & (SEQ - 1);
                        const int h = n >> 6, d = n & (HD - 1);
                        Out[((((size_t)b * HEADS + h) * SEQ + s) << 6) + d] = (TOut)v;
                    } else {
                        Out[(size_t)mm * HID + n] = (TOut)v;
                    }
                }
            }
        }
    }
}

// ---------------------------------------------------------------------------
// Fast GEMM (fp16 A and W): Out = A @ W^T + bias.
// 128x128 tile, BK=32, 256 thr (4 waves 2x2), mfma 16x16x32 f16.
// T4 COUNTED-VMCNT PIPELINE (m218 lever): 4 LDS buffers, 3 tiles in flight,
// raw s_barrier + s_waitcnt vmcnt(8) in the main loop (NEVER 0) -> the wait
// at step t covers loads issued ~3 compute-phases (~750cy) earlier, so the
// per-step HBM drain that capped R4/R6 (~500cy exposed per barrier via
// __syncthreads' implicit vmcnt(0)) disappears.
// RACE ANALYSIS: stage(t+3) placed AFTER barrier_t; its buffer == buffer
// (t-1), whose compute every wave finished before reaching barrier_t (program
// order).  Each wave's own VM_WAIT precedes its barrier, so all chunks of
// tile t are published to LDS before any wave reads them.  Tail: 8->4->0.
// XCD swizzle: nwg=512 (%8==0); per-XCD footprint = A-panel 2MB + W 2MB =
// 4MB = one L2 (R5 lesson: concurrent Ws thrash this).
// ---------------------------------------------------------------------------
template <int MODE, typename TOut>
__global__ __launch_bounds__(256) void gemm16(
    const half_t* __restrict__ A, const half_t* __restrict__ W,
    const float* __restrict__ bias, TOut* __restrict__ Out)
{
    __shared__ half_t As[4][128 * 32];   // 32 KB
    __shared__ half_t Bs[4][128 * 32];   // 32 KB

    const int tid  = threadIdx.x;
    const int id   = blockIdx.y * gridDim.x + blockIdx.x;
    const int cpx  = (gridDim.x * gridDim.y) >> 3;
    const int swz  = (id & 7) * cpx + (id >> 3);
    const int m0   = (swz >> 3) * 128;          // gridDim.x == 8
    const int n0   = (swz & 7) * 128;
    const int wave = tid >> 6;
    const int lane = tid & 63;
    const int quad = lane >> 4;
    const int l16  = lane & 15;
    const int wm   = (wave >> 1) * 64;
    const int wn   = (wave & 1) * 64;

    // staging map: wave w owns chunks 2w,2w+1 (16 rows each) of A and B.
    // Lane i -> row c0*16 + (i>>2), half-col (i&3)*8 (16 B). HW writes LDS
    // at wave-uniform base + lane*16 -> layout matches linear [128][32].
    const int c0   = wave * 2;
    const int srow = c0 * 16 + (lane >> 2);
    const int scol = (lane & 3) * 8;
    const half_t* aptr0 = A + (size_t)(m0 + srow) * HID + scol;
    const half_t* aptr1 = aptr0 + (size_t)16 * HID;
    const half_t* bptr0 = W + (size_t)(n0 + srow) * HID + scol;
    const half_t* bptr1 = bptr0 + (size_t)16 * HID;

    floatx4 acc[4][4];
    const floatx4 zero4 = {0.f, 0.f, 0.f, 0.f};
#pragma unroll
    for (int mt = 0; mt < 4; ++mt)
#pragma unroll
        for (int nt = 0; nt < 4; ++nt) acc[mt][nt] = zero4;

    auto stage = [&](int buf, int k0) {
        gl_lds16(aptr0 + k0, &As[buf][c0 * 512]);
        gl_lds16(aptr1 + k0, &As[buf][c0 * 512 + 512]);
        gl_lds16(bptr0 + k0, &Bs[buf][c0 * 512]);
        gl_lds16(bptr1 + k0, &Bs[buf][c0 * 512 + 512]);
    };
    auto compute = [&](int buf) {
        halfx8 af[4], bfr[4];
#pragma unroll
        for (int t = 0; t < 4; ++t) {
            af[t]  = *(const halfx8*)&As[buf][(wm + t * 16 + l16) * 32 + quad * 8];
            bfr[t] = *(const halfx8*)&Bs[buf][(wn + t * 16 + l16) * 32 + quad * 8];
        }
#pragma unroll
        for (int mt = 0; mt < 4; ++mt)
#pragma unroll
            for (int nt = 0; nt < 4; ++nt)
                acc[mt][nt] = MFMA_F16(af[mt], bfr[nt], acc[mt][nt], 0, 0, 0);
    };

    // prologue: 3 tiles in flight (12 outstanding loads per wave)
    stage(0, 0);
    stage(1, 32);
    stage(2, 64);
    // K = 1024 -> 32 steps.  Outstanding tiles before the wait at step t:
    // min(t+2,31) - (t-1) -> t<=29: 3 (12 loads, wait 8 retires tile t);
    // t=30: 2 (wait 4); t=31: 1 (wait 0).
    for (int t = 0; t < 32; ++t) {
        if (t < 30)       VM_WAIT(8);
        else if (t == 30) VM_WAIT(4);
        else              VM_WAIT(0);
        BARRIER();
        if (t < 29) stage((t + 3) & 3, (t + 3) * 32);
        compute(t & 3);
    }

    epilogue_store<MODE, TOut>(acc, bias, Out, m0, n0, wm, wn, quad, l16);
}

// ---------------------------------------------------------------------------
// Legacy GEMM (fp32 A/W, reg-staged cvt) — fallback if ws too small for the
// fp16 pre-convert path.
// ---------------------------------------------------------------------------
template <int MODE, typename TA, typename TOut>
__global__ __launch_bounds__(256) void gemm_bt(
    const TA* __restrict__ A, const float* __restrict__ W,
    const float* __restrict__ bias, TOut* __restrict__ Out)
{
    __shared__ half_t As[128][40];
    __shared__ half_t Bs[128][40];

    const int tid  = threadIdx.x;
    const int m0   = blockIdx.y * 128;
    const int n0   = blockIdx.x * 128;
    const int wave = tid >> 6;
    const int lane = tid & 63;
    const int quad = lane >> 4;
    const int l16  = lane & 15;
    const int wm   = (wave >> 1) * 64;
    const int wn   = (wave & 1) * 64;
    const int trow = tid >> 1;
    const int tcol = (tid & 1) * 16;

    const TA*    aptr = A + (size_t)(m0 + trow) * HID + tcol;
    const float* bptr = W + (size_t)(n0 + trow) * HID + tcol;

    floatx4 acc[4][4];
    const floatx4 zero4 = {0.f, 0.f, 0.f, 0.f};
#pragma unroll
    for (int mt = 0; mt < 4; ++mt)
#pragma unroll
        for (int nt = 0; nt < 4; ++nt) acc[mt][nt] = zero4;

    for (int k0 = 0; k0 < HID; k0 += 32) {
        halfx8 av0 = load8h(aptr);
        halfx8 av1 = load8h(aptr + 8);
        halfx8 bv0 = load8h(bptr);
        halfx8 bv1 = load8h(bptr + 8);
        aptr += 32;
        bptr += 32;

        __syncthreads();
        *(halfx8*)&As[trow][tcol]     = av0;
        *(halfx8*)&As[trow][tcol + 8] = av1;
        *(halfx8*)&Bs[trow][tcol]     = bv0;
        *(halfx8*)&Bs[trow][tcol + 8] = bv1;
        __syncthreads();

        halfx8 af[4], bfr[4];
#pragma unroll
        for (int t = 0; t < 4; ++t) {
            af[t]  = *(const halfx8*)&As[wm + t * 16 + l16][quad * 8];
            bfr[t] = *(const halfx8*)&Bs[wn + t * 16 + l16][quad * 8];
        }
#pragma unroll
        for (int mt = 0; mt < 4; ++mt)
#pragma unroll
            for (int nt = 0; nt < 4; ++nt)
                acc[mt][nt] = MFMA_F16(af[mt], bfr[nt], acc[mt][nt], 0, 0, 0);
    }

    epilogue_store<MODE, TOut>(acc, bias, Out, m0, n0, wm, wn, quad, l16);
}

// ---------------------------------------------------------------------------
// fp32 -> fp16 conversion kernels (memory-bound, vectorized 8/thread).
// cvt_act3: one launch converts q, k, v (blockIdx.y selects).
// ---------------------------------------------------------------------------
__global__ __launch_bounds__(256) void cvt_act3(
    const float* __restrict__ q, const float* __restrict__ k,
    const float* __restrict__ v,
    half_t* __restrict__ q16, half_t* __restrict__ k16, half_t* __restrict__ v16)
{
    const int t = blockIdx.y;
    const float* src = (t == 0) ? q : (t == 1) ? k : v;
    half_t* dst = (t == 0) ? q16 : (t == 1) ? k16 : v16;
    const size_t i = ((size_t)blockIdx.x * 256 + threadIdx.x) * 8;
    *(halfx8*)(dst + i) = load8h(src + i);
}

__global__ __launch_bounds__(256) void cvt_w4(
    const float* __restrict__ w0, const float* __restrict__ w1,
    const float* __restrict__ w2, const float* __restrict__ w3,
    half_t* __restrict__ out)
{
    const int t = blockIdx.y;
    const float* src = (t == 0) ? w0 : (t == 1) ? w1 : (t == 2) ? w2 : w3;
    const size_t i = ((size_t)blockIdx.x * 256 + threadIdx.x) * 8;
    *(halfx8*)(out + (size_t)t * NWELEM + i) = load8h(src + i);
}

// ---------------------------------------------------------------------------
// Causal flash attention, fp16, swapped-QK^T (in-register softmax).
// R7-proven base (permlane transpose) + permlane REDUCTIONS replacing the
// last shfl_xor DS ops (zero cross-lane DS in the softmax path now).
// T13 defer-max + T14 async K/V staging unchanged.
// ---------------------------------------------------------------------------
__global__ __launch_bounds__(256) void attn_kernel(
    const half_t* __restrict__ Q, const half_t* __restrict__ K,
    const half_t* __restrict__ VT, half_t* __restrict__ O)
{
    __shared__ half_t Ks[64][72];      // [k][d]
    __shared__ half_t Vt[64][72];      // [d][k]

    const int bh  = blockIdx.x;                      // b*HEADS + h
    const int qt  = (gridDim.y - 1) - blockIdx.y;    // heaviest tiles first
    const int q0  = qt * 128;
    const int tid = threadIdx.x;
    const int wave = tid >> 6;
    const int lane = tid & 63;
    const int quad = lane >> 4;
    const int l16  = lane & 15;

    const half_t* Qb  = Q  + (size_t)bh * SEQ * HD;
    const half_t* Kb  = K  + (size_t)bh * SEQ * HD;
    const half_t* VTb = VT + (size_t)bh * HD * SEQ;

    // Q fragments (B-operand of swapped QK^T): B[n=q=l16][k=d=quad*8+j]
    halfx8 aq[2][2];
#pragma unroll
    for (int mt = 0; mt < 2; ++mt) {
        const half_t* p = Qb + (size_t)(q0 + wave * 32 + mt * 16 + l16) * HD + quad * 8;
        aq[mt][0] = *(const halfx8*)p;
        aq[mt][1] = *(const halfx8*)(p + 32);
    }

    const floatx4 zero4 = {0.f, 0.f, 0.f, 0.f};
    floatx4 oaccT[2][4];   // [mt][dt]: lane holds O[q=mt*16+l16][d=dt*16+quad*4+r]
    float mrow[2], lrow[2];
#pragma unroll
    for (int mt = 0; mt < 2; ++mt) {
        mrow[mt] = -3.0e38f;
        lrow[mt] = 0.f;
#pragma unroll
        for (int dt = 0; dt < 4; ++dt) oaccT[mt][dt] = zero4;
    }

    const int srow = tid >> 2;         // 0..63
    const int scol = (tid & 3) * 16;   // 0,16,32,48
    const int ktiles = 2 * qt + 2;

    union U8 { halfx8 h; uint32_t u[4]; };

    // T14 prologue: tile 0 K/V -> regs
    halfx8 nk0, nk1, nv0, nv1;
    {
        const half_t* ksrc = Kb + (size_t)srow * HD + scol;
        nk0 = *(const halfx8*)ksrc;
        nk1 = *(const halfx8*)(ksrc + 8);
        const half_t* vsrc = VTb + (size_t)srow * SEQ + scol;
        nv0 = *(const halfx8*)vsrc;
        nv1 = *(const halfx8*)(vsrc + 8);
    }

    for (int kt = 0; kt < ktiles; ++kt) {
        const int k0 = kt * 64;
        __syncthreads();  // prior iter's Ks/Vt reads done
        *(halfx8*)&Ks[srow][scol]     = nk0;
        *(halfx8*)&Ks[srow][scol + 8] = nk1;
        *(halfx8*)&Vt[srow][scol]     = nv0;
        *(halfx8*)&Vt[srow][scol + 8] = nv1;
        __syncthreads();

        // T14: issue next tile's global loads before this tile's compute
        if (kt + 1 < ktiles) {
            const int kn = k0 + 64;
            const half_t* ksrc = Kb + (size_t)(kn + srow) * HD + scol;
            nk0 = *(const halfx8*)ksrc;
            nk1 = *(const halfx8*)(ksrc + 8);
            const half_t* vsrc = VTb + (size_t)srow * SEQ + kn + scol;
            nv0 = *(const halfx8*)vsrc;
            nv1 = *(const halfx8*)(vsrc + 8);
        }

        // wave-uniform activity predicate (no continue: barriers stay uniform)
        const bool active = (k0 <= q0 + wave * 32 + 31);

        if (active) {
            // S^T: sacc[mt][nt] rows kv, cols q (swapped operands)
            floatx4 sacc[2][4];
#pragma unroll
            for (int mt = 0; mt < 2; ++mt)
#pragma unroll
                for (int nt = 0; nt < 4; ++nt) sacc[mt][nt] = zero4;
#pragma unroll
            for (int nt = 0; nt < 4; ++nt) {
                halfx8 bk0 = *(const halfx8*)&Ks[nt * 16 + l16][quad * 8];
                halfx8 bk1 = *(const halfx8*)&Ks[nt * 16 + l16][quad * 8 + 32];
#pragma unroll
                for (int mt = 0; mt < 2; ++mt) {
                    sacc[mt][nt] = MFMA_F16(bk0, aq[mt][0], sacc[mt][nt], 0, 0, 0);
                    sacc[mt][nt] = MFMA_F16(bk1, aq[mt][1], sacc[mt][nt], 0, 0, 0);
                }
            }

            if (kt >= 2 * qt) {  // diagonal region: mask kv > q
#pragma unroll
                for (int mt = 0; mt < 2; ++mt) {
                    const int qg = q0 + wave * 32 + mt * 16 + l16;
#pragma unroll
                    for (int nt = 0; nt < 4; ++nt) {
                        const int kg = k0 + nt * 16 + quad * 4;
#pragma unroll
                        for (int r = 0; r < 4; ++r)
                            if (kg + r > qg) sacc[mt][nt][r] = -1.0e30f;
                    }
                }
            }

            // in-register online softmax (per lane = per q row, 16 vals);
            // cross-quad combine via permlane (pure VALU, zero DS)
            uint32_t pk[2][4][2];
#pragma unroll
            for (int mt = 0; mt < 2; ++mt) {
                float mx = sacc[mt][0][0];
#pragma unroll
                for (int nt = 0; nt < 4; ++nt)
#pragma unroll
                    for (int r = 0; r < 4; ++r)
                        if (nt | r) mx = fmaxf(mx, sacc[mt][nt][r]);
                mx = quad_max(mx);

                // T13 defer-max: skip rescale while tile max lags running
                // max by <= 8 (P <= e^8 = 2981 fits fp16; fp32 accum).
                if (!__all(mx <= mrow[mt] + 8.f)) {
                    const float mnew  = fmaxf(mrow[mt], mx);
                    const float alpha = __expf(mrow[mt] - mnew);
                    mrow[mt] = mnew;
                    lrow[mt] *= alpha;
#pragma unroll
                    for (int dt = 0; dt < 4; ++dt) oaccT[mt][dt] *= alpha;
                }

                float rsum = 0.f;
#pragma unroll
                for (int nt = 0; nt < 4; ++nt)
#pragma unroll
                    for (int r = 0; r < 4; ++r) {
                        const float p = __expf(sacc[mt][nt][r] - mrow[mt]);
                        sacc[mt][nt][r] = p;
                        rsum += p;
                    }
#pragma unroll
                for (int nt = 0; nt < 4; ++nt) {
                    pk[mt][nt][0] = pack2h(sacc[mt][nt][0], sacc[mt][nt][1]);
                    pk[mt][nt][1] = pack2h(sacc[mt][nt][2], sacc[mt][nt][3]);
                }
                lrow[mt] += quad_sum(rsum);
            }

            // quad-transpose P^T -> PV B-frag [n=q=l16][k=kv=quad*8+j] via
            // permlane (R7-proven; operands are distinct MFMA results so no
            // register-alias hazard):
            //   pl32swap: A'=[A.r0,A.r1,B.r0,B.r1], B'=[A.r2,A.r3,B.r2,B.r3]
            //   pl16swap: A''=[A.r0,A.r2,B.r0,B.r2], B''=[A.r1,A.r3,B.r1,B.r3]
            U8 pb[2][2];  // [mt][s2]
#pragma unroll
            for (int mt = 0; mt < 2; ++mt)
#pragma unroll
                for (int s2 = 0; s2 < 2; ++s2)
#pragma unroll
                    for (int h = 0; h < 2; ++h) {
                        uint32_t a = pk[mt][2 * s2][h];
                        uint32_t b = pk[mt][2 * s2 + 1][h];
                        pl32swap(a, b);
                        pl16swap(a, b);
                        pb[mt][s2].u[h]     = a;
                        pb[mt][s2].u[2 + h] = b;
                    }

            // PV: O^T = MFMA(A=V^T frag, B=P frag)
#pragma unroll
            for (int s2 = 0; s2 < 2; ++s2)
#pragma unroll
                for (int dt = 0; dt < 4; ++dt) {
                    halfx8 bv = *(const halfx8*)&Vt[dt * 16 + l16][s2 * 32 + quad * 8];
                    oaccT[0][dt] = MFMA_F16(bv, pb[0][s2].h, oaccT[0][dt], 0, 0, 0);
                    oaccT[1][dt] = MFMA_F16(bv, pb[1][s2].h, oaccT[1][dt], 0, 0, 0);
                }
        }
    }

    // epilogue: O^T fragment -> Ob[b][q][h*64+d], halfx4 along d
    const int b = bh >> 4, h = bh & (HEADS - 1);
#pragma unroll
    for (int mt = 0; mt < 2; ++mt) {
        const int q = q0 + wave * 32 + mt * 16 + l16;
#pragma unroll
        for (int dt = 0; dt < 4; ++dt) {
            halfx4 st;
#pragma unroll
            for (int r = 0; r < 4; ++r)
                st[r] = (half_t)(oaccT[mt][dt][r] / lrow[mt]);
            *(halfx4*)(O + (size_t)(b * SEQ + q) * HID +
                       h * HD + dt * 16 + quad * 4) = st;
        }
    }
}

// ---------------------------------------------------------------------------
extern "C" void kernel_launch(void* const* d_in, const int* in_sizes, int n_in,
                              void* d_out, int out_size, void* d_ws, size_t ws_size,
                              hipStream_t stream)
{
    const float* query = (const float*)d_in[0];
    const float* key   = (const float*)d_in[1];
    const float* value = (const float*)d_in[2];
    const float* Wq    = (const float*)d_in[3];
    const float* bq    = (const float*)d_in[4];
    const float* Wk    = (const float*)d_in[5];
    const float* bk    = (const float*)d_in[6];
    const float* Wv    = (const float*)d_in[7];
    const float* bv    = (const float*)d_in[8];
    const float* Wo    = (const float*)d_in[9];
    const float* bo    = (const float*)d_in[10];
    float* out = (float*)d_out;

    // workspace (fp16): Qp, Kp [B][H][S][D]; VpT [B][H][D][S]; Ob [M][HID];
    // W16 [4][HID][HID] = 75.5 MB (proven R1-R7).  Activations live together
    // (single cvt launch): q16/k16 in d_out scratch (2*NE*2B == out_size;
    // d_out dead until gemm_final rewrites all of it — proven R5-R7), v16 in
    // the Ob slot (dead until attn).  GEMMs run SERIALLY (R5 L2 lesson).
    const size_t NE = (size_t)MTOT * HID;
    half_t* Qp  = (half_t*)d_ws;
    half_t* Kp  = Qp  + NE;
    half_t* VpT = Kp  + NE;
    half_t* Ob  = VpT + NE;
    half_t* W16 = Ob  + NE;
    const size_t need = (4 * NE + 4 * (size_t)NWELEM) * sizeof(half_t);

    dim3 gg(HID / 128, MTOT / 128);     // (8, 64)
    dim3 ga(BATCH * HEADS, SEQ / 128);  // (64, 16)

    if (ws_size >= need && (size_t)out_size >= 2 * NE * sizeof(half_t)) {
        half_t* q16 = (half_t*)out;       // d_out scratch
        half_t* k16 = q16 + NE;
        half_t* v16 = Ob;                 // Ob slot scratch
        const unsigned actBlocks = (unsigned)(NE / 2048);      // 4096
        const unsigned wBlocks   = (unsigned)(NWELEM / 2048);  // 512

        cvt_w4<<<dim3(wBlocks, 4), 256, 0, stream>>>(Wq, Wk, Wv, Wo, W16);
        cvt_act3<<<dim3(actBlocks, 3), 256, 0, stream>>>(
            query, key, value, q16, k16, v16);

        gemm16<0, half_t><<<gg, 256, 0, stream>>>(q16, W16, bq, Qp);
        gemm16<0, half_t><<<gg, 256, 0, stream>>>(k16, W16 + NWELEM, bk, Kp);
        gemm16<2, half_t><<<gg, 256, 0, stream>>>(v16, W16 + 2 * (size_t)NWELEM, bv, VpT);

        attn_kernel<<<ga, 256, 0, stream>>>(Qp, Kp, VpT, Ob);

        gemm16<1, float><<<gg, 256, 0, stream>>>(Ob, W16 + 3 * (size_t)NWELEM, bo, out);
    } else {
        // legacy fallback path
        gemm_bt<0, float, half_t><<<gg, 256, 0, stream>>>(query, Wq, bq, Qp);
        gemm_bt<0, float, half_t><<<gg, 256, 0, stream>>>(key,   Wk, bk, Kp);
        gemm_bt<2, float, half_t><<<gg, 256, 0, stream>>>(value, Wv, bv, VpT);
        attn_kernel<<<ga, 256, 0, stream>>>(Qp, Kp, VpT, Ob);
        gemm_bt<1, half_t, float><<<gg, 256, 0, stream>>>(Ob, Wo, bo, out);
    }
}

// Round 9
// 419.477 us; speedup vs baseline: 1.0375x; 1.0005x over previous
//
#include <hip/hip_runtime.h>
#include <hip/hip_fp16.h>

typedef _Float16 half_t;
typedef half_t halfx8 __attribute__((ext_vector_type(8)));
typedef half_t halfx4 __attribute__((ext_vector_type(4)));
typedef float floatx4 __attribute__((ext_vector_type(4)));

#define HID 1024
#define HEADS 16
#define HD 64
#define BATCH 4
#define SEQ 2048
#define MTOT (BATCH * SEQ) /* 8192 */
#define NWELEM (HID * HID) /* 1048576 */

#define MFMA_F16 __builtin_amdgcn_mfma_f32_16x16x32_f16

// Load 8 contiguous elements as halfx8; fp32 source converts on the fly.
__device__ inline halfx8 load8h(const half_t* p) { return *(const halfx8*)p; }
__device__ inline halfx8 load8h(const float* p) {
    floatx4 x = *(const floatx4*)p;
    floatx4 y = *(const floatx4*)(p + 4);
    halfx8 r;
    r[0] = (half_t)x[0]; r[1] = (half_t)x[1];
    r[2] = (half_t)x[2]; r[3] = (half_t)x[3];
    r[4] = (half_t)y[0]; r[5] = (half_t)y[1];
    r[6] = (half_t)y[2]; r[7] = (half_t)y[3];
    return r;
}

// pack two fp32 -> one dword of 2 fp16 (RTN, matches (half_t) cast numerics)
__device__ __forceinline__ uint32_t pack2h(float a, float b) {
    union { half_t h[2]; uint32_t u; } r;
    r.h[0] = (half_t)a; r.h[1] = (half_t)b;
    return r.u;
}

// async 16B global->LDS: LDS dest is wave-uniform base + lane*16 (m104/m173);
// global src is per-lane. size arg must be a literal (16).
__device__ __forceinline__ void gl_lds16(const half_t* g, half_t* lds) {
    __builtin_amdgcn_global_load_lds(
        (const __attribute__((address_space(1))) void*)g,
        (__attribute__((address_space(3))) void*)lds, 16, 0, 0);
}

// --- gfx950 permlane swaps (VALU cross-lane, zero DS) ----------------------
// v_permlane32_swap_b32 a,b: a[32:63] <-> b[0:31]
//   => a' = [a.lo, b.lo], b' = [a.hi, b.hi]   (16-lane rows: lo=r0r1, hi=r2r3)
// v_permlane16_swap_b32 a,b: a's odd 16-lane rows <-> b's even rows
//   => a' = [a.r0, b.r0, a.r2, b.r2], b' = [a.r1, b.r1, a.r3, b.r3]
// Semantics HW-validated (R7/R8 passing).
// SAFETY (R3 post-mortem): operands MUST occupy distinct VGPRs; identical
// SSA values get CSE'd into one register and the swap self-corrupts.  For
// self-reductions we force materialization with an explicit v_mov asm.
__device__ __forceinline__ void pl32swap(uint32_t& a, uint32_t& b) {
    asm volatile("v_permlane32_swap_b32 %0, %1" : "+v"(a), "+v"(b));
}
__device__ __forceinline__ void pl16swap(uint32_t& a, uint32_t& b) {
    asm volatile("v_permlane16_swap_b32 %0, %1" : "+v"(a), "+v"(b));
}
// cross-quad max/sum (lanes sharing l16); result in every lane.  Pure VALU.
__device__ __forceinline__ float quad_max(float x) {
    uint32_t a = __builtin_bit_cast(uint32_t, x), b;
    asm volatile("v_mov_b32 %0, %1" : "=v"(b) : "v"(a));
    pl16swap(a, b);   // a=[r0,r0,r2,r2], b=[r1,r1,r3,r3]
    float m = fmaxf(__builtin_bit_cast(float, a), __builtin_bit_cast(float, b));
    uint32_t c = __builtin_bit_cast(uint32_t, m), d;
    asm volatile("v_mov_b32 %0, %1" : "=v"(d) : "v"(c));
    pl32swap(c, d);   // c=[lo,lo], d=[hi,hi]
    return fmaxf(__builtin_bit_cast(float, c), __builtin_bit_cast(float, d));
}
__device__ __forceinline__ float quad_sum(float x) {
    uint32_t a = __builtin_bit_cast(uint32_t, x), b;
    asm volatile("v_mov_b32 %0, %1" : "=v"(b) : "v"(a));
    pl16swap(a, b);
    float s = __builtin_bit_cast(float, a) + __builtin_bit_cast(float, b);
    uint32_t c = __builtin_bit_cast(uint32_t, s), d;
    asm volatile("v_mov_b32 %0, %1" : "=v"(d) : "v"(c));
    pl32swap(c, d);
    return __builtin_bit_cast(float, c) + __builtin_bit_cast(float, d);
}

// ---------------------------------------------------------------------------
// GEMM epilogue for the 128x64-tile kernel (acc[4][2]).  C/D layout:
// col = lane&15, row = quad*4 + reg  [m89-verified].
// MODE 0: fp16 -> [B][H][S][D]   (Q, K)
// MODE 1: fp32 -> flat [M, N]    (final)
// MODE 2: fp16 -> [B][H][D][S]   (V transposed; 8B-aligned halfx4 stores)
// ---------------------------------------------------------------------------
template <int MODE, typename TOut>
__device__ __forceinline__ void epilogue_store42(
    const floatx4 (&acc)[4][2], const float* __restrict__ bias,
    TOut* __restrict__ Out, int m0, int n0, int wm, int wn, int quad, int l16)
{
    float bvals[2];
#pragma unroll
    for (int nt = 0; nt < 2; ++nt)
        bvals[nt] = bias[n0 + wn + nt * 16 + l16];

#pragma unroll
    for (int mt = 0; mt < 4; ++mt) {
        const int mbase = m0 + wm + mt * 16 + quad * 4;
#pragma unroll
        for (int nt = 0; nt < 2; ++nt) {
            const int n = n0 + wn + nt * 16 + l16;
            if (MODE == 2) {
                const int b = mbase >> 11, s = mbase & (SEQ - 1);
                const int h = n >> 6, d = n & (HD - 1);
                halfx4 st;
#pragma unroll
                for (int r = 0; r < 4; ++r)
                    st[r] = (half_t)(acc[mt][nt][r] + bvals[nt]);
                *(halfx4*)((half_t*)Out +
                    ((((size_t)b * HEADS + h) * HD + d) << 11) + s) = st;
            } else {
#pragma unroll
                for (int r = 0; r < 4; ++r) {
                    const float v = acc[mt][nt][r] + bvals[nt];
                    const int mm  = mbase + r;
                    if (MODE == 0) {
                        const int b = mm >> 11, s = mm & (SEQ - 1);
                        const int h = n >> 6, d = n & (HD - 1);
                        Out[((((size_t)b * HEADS + h) * SEQ + s) << 6) + d] = (TOut)v;
                    } else {
                        Out[(size_t)mm * HID + n] = (TOut)v;
                    }
                }
            }
        }
    }
}

// ---------------------------------------------------------------------------
// Fast GEMM (fp16 A and W): Out = A @ W^T + bias.
// 128x64 tile (R9: BN 128->64), BK=32, 256 thr (4 waves 2x2, wave tile
// 64x32), mfma 16x16x32 f16, R4-PROVEN 2-barrier double-buffered loop.
// WHY BN=64: grid (16,64) = 1024 blocks = 4 blocks/CU (vs 2 at BN=128).
// R4/R6/R8 showed within-block pipelining (dbuf, BK=64, counted vmcnt) is
// all defeated by the compiler's conservative vmcnt(0)-before-ds_read /
// barrier drain; the drain is only hidden by OTHER co-resident blocks
// (m114 cross-block overlap, the mechanism behind m97's 874 TF at 3-4
// blocks/CU).  LDS 24 KB/block (4x24=96<160 ✓), acc 32 VGPR.
// XCD swizzle: 1024 blocks (%8==0); per-XCD footprint = 8 m-panels (2MB A)
// x all n (2MB W) = 4MB = one L2 (R5 lesson).
// ---------------------------------------------------------------------------
template <int MODE, typename TOut>
__global__ __launch_bounds__(256) void gemm16(
    const half_t* __restrict__ A, const half_t* __restrict__ W,
    const float* __restrict__ bias, TOut* __restrict__ Out)
{
    __shared__ half_t As[2][128 * 32];   // 8 KB per buffer
    __shared__ half_t Bs[2][64 * 32];    // 4 KB per buffer

    const int tid  = threadIdx.x;
    const int id   = blockIdx.y * gridDim.x + blockIdx.x;   // gridDim.x = 16
    const int cpx  = (gridDim.x * gridDim.y) >> 3;          // 128
    const int swz  = (id & 7) * cpx + (id >> 3);
    const int m0   = (swz >> 4) * 128;
    const int n0   = (swz & 15) * 64;
    const int wave = tid >> 6;
    const int lane = tid & 63;
    const int quad = lane >> 4;
    const int l16  = lane & 15;
    const int wm   = (wave >> 1) * 64;
    const int wn   = (wave & 1) * 32;

    // A staging: wave w owns chunks 2w,2w+1 (16 rows each; rows [32w,32w+32)).
    // Lane i -> row chunkbase + (i>>2), half-col (i&3)*8 (16 B).  HW writes
    // LDS at wave-uniform base + lane*16 -> layout matches linear [128][32].
    const int c0   = wave * 2;
    const int arow = c0 * 16 + (lane >> 2);
    const int scol = (lane & 3) * 8;
    const half_t* aptr0 = A + (size_t)(m0 + arow) * HID + scol;
    const half_t* aptr1 = aptr0 + (size_t)16 * HID;
    // B staging: wave w owns rows [16w, 16w+16) of the 64-row W panel.
    const int brow = wave * 16 + (lane >> 2);
    const half_t* bptr0 = W + (size_t)(n0 + brow) * HID + scol;

    floatx4 acc[4][2];
    const floatx4 zero4 = {0.f, 0.f, 0.f, 0.f};
#pragma unroll
    for (int mt = 0; mt < 4; ++mt)
#pragma unroll
        for (int nt = 0; nt < 2; ++nt) acc[mt][nt] = zero4;

    auto stage = [&](int buf, int k0) {
        gl_lds16(aptr0 + k0, &As[buf][c0 * 512]);
        gl_lds16(aptr1 + k0, &As[buf][c0 * 512 + 512]);
        gl_lds16(bptr0 + k0, &Bs[buf][wave * 512]);
    };
    auto compute = [&](int buf) {
        halfx8 af[4], bfr[2];
#pragma unroll
        for (int t = 0; t < 4; ++t)
            af[t]  = *(const halfx8*)&As[buf][(wm + t * 16 + l16) * 32 + quad * 8];
#pragma unroll
        for (int t = 0; t < 2; ++t)
            bfr[t] = *(const halfx8*)&Bs[buf][(wn + t * 16 + l16) * 32 + quad * 8];
#pragma unroll
        for (int mt = 0; mt < 4; ++mt)
#pragma unroll
            for (int nt = 0; nt < 2; ++nt)
                acc[mt][nt] = MFMA_F16(af[mt], bfr[nt], acc[mt][nt], 0, 0, 0);
    };

    stage(0, 0);
    __syncthreads();              // implicit vmcnt(0): tile 0 resident
    for (int k0 = 0; k0 < HID; k0 += 64) {
        stage(1, k0 + 32);        // prefetch while computing buf 0
        compute(0);
        __syncthreads();          // drain: prefetch landed; buf0 reads done
        if (k0 + 64 < HID) stage(0, k0 + 64);
        compute(1);
        __syncthreads();
    }

    epilogue_store42<MODE, TOut>(acc, bias, Out, m0, n0, wm, wn, quad, l16);
}

// ---------------------------------------------------------------------------
// Legacy GEMM (fp32 A/W, reg-staged cvt) — fallback if ws too small for the
// fp16 pre-convert path.  128x128 tile, grid (8,64).
// ---------------------------------------------------------------------------
template <int MODE, typename TA, typename TOut>
__global__ __launch_bounds__(256) void gemm_bt(
    const TA* __restrict__ A, const float* __restrict__ W,
    const float* __restrict__ bias, TOut* __restrict__ Out)
{
    __shared__ half_t As[128][40];
    __shared__ half_t Bs[128][40];

    const int tid  = threadIdx.x;
    const int m0   = blockIdx.y * 128;
    const int n0   = blockIdx.x * 128;
    const int wave = tid >> 6;
    const int lane = tid & 63;
    const int quad = lane >> 4;
    const int l16  = lane & 15;
    const int wm   = (wave >> 1) * 64;
    const int wn   = (wave & 1) * 64;
    const int trow = tid >> 1;
    const int tcol = (tid & 1) * 16;

    const TA*    aptr = A + (size_t)(m0 + trow) * HID + tcol;
    const float* bptr = W + (size_t)(n0 + trow) * HID + tcol;

    floatx4 acc[4][4];
    const floatx4 zero4 = {0.f, 0.f, 0.f, 0.f};
#pragma unroll
    for (int mt = 0; mt < 4; ++mt)
#pragma unroll
        for (int nt = 0; nt < 4; ++nt) acc[mt][nt] = zero4;

    for (int k0 = 0; k0 < HID; k0 += 32) {
        halfx8 av0 = load8h(aptr);
        halfx8 av1 = load8h(aptr + 8);
        halfx8 bv0 = load8h(bptr);
        halfx8 bv1 = load8h(bptr + 8);
        aptr += 32;
        bptr += 32;

        __syncthreads();
        *(halfx8*)&As[trow][tcol]     = av0;
        *(halfx8*)&As[trow][tcol + 8] = av1;
        *(halfx8*)&Bs[trow][tcol]     = bv0;
        *(halfx8*)&Bs[trow][tcol + 8] = bv1;
        __syncthreads();

        halfx8 af[4], bfr[4];
#pragma unroll
        for (int t = 0; t < 4; ++t) {
            af[t]  = *(const halfx8*)&As[wm + t * 16 + l16][quad * 8];
            bfr[t] = *(const halfx8*)&Bs[wn + t * 16 + l16][quad * 8];
        }
#pragma unroll
        for (int mt = 0; mt < 4; ++mt)
#pragma unroll
            for (int nt = 0; nt < 4; ++nt)
                acc[mt][nt] = MFMA_F16(af[mt], bfr[nt], acc[mt][nt], 0, 0, 0);
    }

    float bvals[4];
#pragma unroll
    for (int nt = 0; nt < 4; ++nt)
        bvals[nt] = bias[n0 + wn + nt * 16 + l16];
#pragma unroll
    for (int mt = 0; mt < 4; ++mt) {
        const int mbase = m0 + wm + mt * 16 + quad * 4;
#pragma unroll
        for (int nt = 0; nt < 4; ++nt) {
            const int n = n0 + wn + nt * 16 + l16;
            if (MODE == 2) {
                const int b = mbase >> 11, s = mbase & (SEQ - 1);
                const int h = n >> 6, d = n & (HD - 1);
                halfx4 st;
#pragma unroll
                for (int r = 0; r < 4; ++r)
                    st[r] = (half_t)(acc[mt][nt][r] + bvals[nt]);
                *(halfx4*)((half_t*)Out +
                    ((((size_t)b * HEADS + h) * HD + d) << 11) + s) = st;
            } else {
#pragma unroll
                for (int r = 0; r < 4; ++r) {
                    const float v = acc[mt][nt][r] + bvals[nt];
                    const int mm  = mbase + r;
                    if (MODE == 0) {
                        const int b = mm >> 11, s = mm & (SEQ - 1);
                        const int h = n >> 6, d = n & (HD - 1);
                        Out[((((size_t)b * HEADS + h) * SEQ + s) << 6) + d] = (TOut)v;
                    } else {
                        Out[(size_t)mm * HID + n] = (TOut)v;
                    }
                }
            }
        }
    }
}

// ---------------------------------------------------------------------------
// fp32 -> fp16 conversion kernels (memory-bound, vectorized 8/thread).
// cvt_act3: one launch converts q, k, v (blockIdx.y selects).
// ---------------------------------------------------------------------------
__global__ __launch_bounds__(256) void cvt_act3(
    const float* __restrict__ q, const float* __restrict__ k,
    const float* __restrict__ v,
    half_t* __restrict__ q16, half_t* __restrict__ k16, half_t* __restrict__ v16)
{
    const int t = blockIdx.y;
    const float* src = (t == 0) ? q : (t == 1) ? k : v;
    half_t* dst = (t == 0) ? q16 : (t == 1) ? k16 : v16;
    const size_t i = ((size_t)blockIdx.x * 256 + threadIdx.x) * 8;
    *(halfx8*)(dst + i) = load8h(src + i);
}

__global__ __launch_bounds__(256) void cvt_w4(
    const float* __restrict__ w0, const float* __restrict__ w1,
    const float* __restrict__ w2, const float* __restrict__ w3,
    half_t* __restrict__ out)
{
    const int t = blockIdx.y;
    const float* src = (t == 0) ? w0 : (t == 1) ? w1 : (t == 2) ? w2 : w3;
    const size_t i = ((size_t)blockIdx.x * 256 + threadIdx.x) * 8;
    *(halfx8*)(out + (size_t)t * NWELEM + i) = load8h(src + i);
}

// ---------------------------------------------------------------------------
// Causal flash attention, fp16, swapped-QK^T (in-register softmax).
// UNCHANGED FROM R8 (proven 88.7 us): permlane transpose + permlane
// reductions (zero cross-lane DS), T13 defer-max, T14 async K/V staging.
// ---------------------------------------------------------------------------
__global__ __launch_bounds__(256) void attn_kernel(
    const half_t* __restrict__ Q, const half_t* __restrict__ K,
    const half_t* __restrict__ VT, half_t* __restrict__ O)
{
    __shared__ half_t Ks[64][72];      // [k][d]
    __shared__ half_t Vt[64][72];      // [d][k]

    const int bh  = blockIdx.x;                      // b*HEADS + h
    const int qt  = (gridDim.y - 1) - blockIdx.y;    // heaviest tiles first
    const int q0  = qt * 128;
    const int tid = threadIdx.x;
    const int wave = tid >> 6;
    const int lane = tid & 63;
    const int quad = lane >> 4;
    const int l16  = lane & 15;

    const half_t* Qb  = Q  + (size_t)bh * SEQ * HD;
    const half_t* Kb  = K  + (size_t)bh * SEQ * HD;
    const half_t* VTb = VT + (size_t)bh * HD * SEQ;

    // Q fragments (B-operand of swapped QK^T): B[n=q=l16][k=d=quad*8+j]
    halfx8 aq[2][2];
#pragma unroll
    for (int mt = 0; mt < 2; ++mt) {
        const half_t* p = Qb + (size_t)(q0 + wave * 32 + mt * 16 + l16) * HD + quad * 8;
        aq[mt][0] = *(const halfx8*)p;
        aq[mt][1] = *(const halfx8*)(p + 32);
    }

    const floatx4 zero4 = {0.f, 0.f, 0.f, 0.f};
    floatx4 oaccT[2][4];   // [mt][dt]: lane holds O[q=mt*16+l16][d=dt*16+quad*4+r]
    float mrow[2], lrow[2];
#pragma unroll
    for (int mt = 0; mt < 2; ++mt) {
        mrow[mt] = -3.0e38f;
        lrow[mt] = 0.f;
#pragma unroll
        for (int dt = 0; dt < 4; ++dt) oaccT[mt][dt] = zero4;
    }

    const int srow = tid >> 2;         // 0..63
    const int scol = (tid & 3) * 16;   // 0,16,32,48
    const int ktiles = 2 * qt + 2;

    union U8 { halfx8 h; uint32_t u[4]; };

    // T14 prologue: tile 0 K/V -> regs
    halfx8 nk0, nk1, nv0, nv1;
    {
        const half_t* ksrc = Kb + (size_t)srow * HD + scol;
        nk0 = *(const halfx8*)ksrc;
        nk1 = *(const halfx8*)(ksrc + 8);
        const half_t* vsrc = VTb + (size_t)srow * SEQ + scol;
        nv0 = *(const halfx8*)vsrc;
        nv1 = *(const halfx8*)(vsrc + 8);
    }

    for (int kt = 0; kt < ktiles; ++kt) {
        const int k0 = kt * 64;
        __syncthreads();  // prior iter's Ks/Vt reads done
        *(halfx8*)&Ks[srow][scol]     = nk0;
        *(halfx8*)&Ks[srow][scol + 8] = nk1;
        *(halfx8*)&Vt[srow][scol]     = nv0;
        *(halfx8*)&Vt[srow][scol + 8] = nv1;
        __syncthreads();

        // T14: issue next tile's global loads before this tile's compute
        if (kt + 1 < ktiles) {
            const int kn = k0 + 64;
            const half_t* ksrc = Kb + (size_t)(kn + srow) * HD + scol;
            nk0 = *(const halfx8*)ksrc;
            nk1 = *(const halfx8*)(ksrc + 8);
            const half_t* vsrc = VTb + (size_t)srow * SEQ + kn + scol;
            nv0 = *(const halfx8*)vsrc;
            nv1 = *(const halfx8*)(vsrc + 8);
        }

        // wave-uniform activity predicate (no continue: barriers stay uniform)
        const bool active = (k0 <= q0 + wave * 32 + 31);

        if (active) {
            // S^T: sacc[mt][nt] rows kv, cols q (swapped operands)
            floatx4 sacc[2][4];
#pragma unroll
            for (int mt = 0; mt < 2; ++mt)
#pragma unroll
                for (int nt = 0; nt < 4; ++nt) sacc[mt][nt] = zero4;
#pragma unroll
            for (int nt = 0; nt < 4; ++nt) {
                halfx8 bk0 = *(const halfx8*)&Ks[nt * 16 + l16][quad * 8];
                halfx8 bk1 = *(const halfx8*)&Ks[nt * 16 + l16][quad * 8 + 32];
#pragma unroll
                for (int mt = 0; mt < 2; ++mt) {
                    sacc[mt][nt] = MFMA_F16(bk0, aq[mt][0], sacc[mt][nt], 0, 0, 0);
                    sacc[mt][nt] = MFMA_F16(bk1, aq[mt][1], sacc[mt][nt], 0, 0, 0);
                }
            }

            if (kt >= 2 * qt) {  // diagonal region: mask kv > q
#pragma unroll
                for (int mt = 0; mt < 2; ++mt) {
                    const int qg = q0 + wave * 32 + mt * 16 + l16;
#pragma unroll
                    for (int nt = 0; nt < 4; ++nt) {
                        const int kg = k0 + nt * 16 + quad * 4;
#pragma unroll
                        for (int r = 0; r < 4; ++r)
                            if (kg + r > qg) sacc[mt][nt][r] = -1.0e30f;
                    }
                }
            }

            // in-register online softmax (per lane = per q row, 16 vals);
            // cross-quad combine via permlane (pure VALU, zero DS)
            uint32_t pk[2][4][2];
#pragma unroll
            for (int mt = 0; mt < 2; ++mt) {
                float mx = sacc[mt][0][0];
#pragma unroll
                for (int nt = 0; nt < 4; ++nt)
#pragma unroll
                    for (int r = 0; r < 4; ++r)
                        if (nt | r) mx = fmaxf(mx, sacc[mt][nt][r]);
                mx = quad_max(mx);

                // T13 defer-max: skip rescale while tile max lags running
                // max by <= 8 (P <= e^8 = 2981 fits fp16; fp32 accum).
                if (!__all(mx <= mrow[mt] + 8.f)) {
                    const float mnew  = fmaxf(mrow[mt], mx);
                    const float alpha = __expf(mrow[mt] - mnew);
                    mrow[mt] = mnew;
                    lrow[mt] *= alpha;
#pragma unroll
                    for (int dt = 0; dt < 4; ++dt) oaccT[mt][dt] *= alpha;
                }

                float rsum = 0.f;
#pragma unroll
                for (int nt = 0; nt < 4; ++nt)
#pragma unroll
                    for (int r = 0; r < 4; ++r) {
                        const float p = __expf(sacc[mt][nt][r] - mrow[mt]);
                        sacc[mt][nt][r] = p;
                        rsum += p;
                    }
#pragma unroll
                for (int nt = 0; nt < 4; ++nt) {
                    pk[mt][nt][0] = pack2h(sacc[mt][nt][0], sacc[mt][nt][1]);
                    pk[mt][nt][1] = pack2h(sacc[mt][nt][2], sacc[mt][nt][3]);
                }
                lrow[mt] += quad_sum(rsum);
            }

            // quad-transpose P^T -> PV B-frag [n=q=l16][k=kv=quad*8+j] via
            // permlane (R7-proven; operands are distinct MFMA results so no
            // register-alias hazard):
            //   pl32swap: A'=[A.r0,A.r1,B.r0,B.r1], B'=[A.r2,A.r3,B.r2,B.r3]
            //   pl16swap: A''=[A.r0,A.r2,B.r0,B.r2], B''=[A.r1,A.r3,B.r1,B.r3]
            U8 pb[2][2];  // [mt][s2]
#pragma unroll
            for (int mt = 0; mt < 2; ++mt)
#pragma unroll
                for (int s2 = 0; s2 < 2; ++s2)
#pragma unroll
                    for (int h = 0; h < 2; ++h) {
                        uint32_t a = pk[mt][2 * s2][h];
                        uint32_t b = pk[mt][2 * s2 + 1][h];
                        pl32swap(a, b);
                        pl16swap(a, b);
                        pb[mt][s2].u[h]     = a;
                        pb[mt][s2].u[2 + h] = b;
                    }

            // PV: O^T = MFMA(A=V^T frag, B=P frag)
#pragma unroll
            for (int s2 = 0; s2 < 2; ++s2)
#pragma unroll
                for (int dt = 0; dt < 4; ++dt) {
                    halfx8 bv = *(const halfx8*)&Vt[dt * 16 + l16][s2 * 32 + quad * 8];
                    oaccT[0][dt] = MFMA_F16(bv, pb[0][s2].h, oaccT[0][dt], 0, 0, 0);
                    oaccT[1][dt] = MFMA_F16(bv, pb[1][s2].h, oaccT[1][dt], 0, 0, 0);
                }
        }
    }

    // epilogue: O^T fragment -> Ob[b][q][h*64+d], halfx4 along d
    const int b = bh >> 4, h = bh & (HEADS - 1);
#pragma unroll
    for (int mt = 0; mt < 2; ++mt) {
        const int q = q0 + wave * 32 + mt * 16 + l16;
#pragma unroll
        for (int dt = 0; dt < 4; ++dt) {
            halfx4 st;
#pragma unroll
            for (int r = 0; r < 4; ++r)
                st[r] = (half_t)(oaccT[mt][dt][r] / lrow[mt]);
            *(halfx4*)(O + (size_t)(b * SEQ + q) * HID +
                       h * HD + dt * 16 + quad * 4) = st;
        }
    }
}

// ---------------------------------------------------------------------------
extern "C" void kernel_launch(void* const* d_in, const int* in_sizes, int n_in,
                              void* d_out, int out_size, void* d_ws, size_t ws_size,
                              hipStream_t stream)
{
    const float* query = (const float*)d_in[0];
    const float* key   = (const float*)d_in[1];
    const float* value = (const float*)d_in[2];
    const float* Wq    = (const float*)d_in[3];
    const float* bq    = (const float*)d_in[4];
    const float* Wk    = (const float*)d_in[5];
    const float* bk    = (const float*)d_in[6];
    const float* Wv    = (const float*)d_in[7];
    const float* bv    = (const float*)d_in[8];
    const float* Wo    = (const float*)d_in[9];
    const float* bo    = (const float*)d_in[10];
    float* out = (float*)d_out;

    // workspace (fp16): Qp, Kp [B][H][S][D]; VpT [B][H][D][S]; Ob [M][HID];
    // W16 [4][HID][HID] = 75.5 MB (proven R1-R8).  Activations live together
    // (single cvt launch): q16/k16 in d_out scratch (2*NE*2B == out_size;
    // d_out dead until the final GEMM rewrites all of it — proven R5-R8),
    // v16 in the Ob slot (dead until attn).  GEMMs run SERIALLY (R5 lesson).
    const size_t NE = (size_t)MTOT * HID;
    half_t* Qp  = (half_t*)d_ws;
    half_t* Kp  = Qp  + NE;
    half_t* VpT = Kp  + NE;
    half_t* Ob  = VpT + NE;
    half_t* W16 = Ob  + NE;
    const size_t need = (4 * NE + 4 * (size_t)NWELEM) * sizeof(half_t);

    dim3 gg(HID / 64, MTOT / 128);      // (16, 64) — 1024 blocks, 4/CU
    dim3 ggL(HID / 128, MTOT / 128);    // (8, 64) legacy
    dim3 ga(BATCH * HEADS, SEQ / 128);  // (64, 16)

    if (ws_size >= need && (size_t)out_size >= 2 * NE * sizeof(half_t)) {
        half_t* q16 = (half_t*)out;       // d_out scratch
        half_t* k16 = q16 + NE;
        half_t* v16 = Ob;                 // Ob slot scratch
        const unsigned actBlocks = (unsigned)(NE / 2048);      // 4096
        const unsigned wBlocks   = (unsigned)(NWELEM / 2048);  // 512

        cvt_w4<<<dim3(wBlocks, 4), 256, 0, stream>>>(Wq, Wk, Wv, Wo, W16);
        cvt_act3<<<dim3(actBlocks, 3), 256, 0, stream>>>(
            query, key, value, q16, k16, v16);

        gemm16<0, half_t><<<gg, 256, 0, stream>>>(q16, W16, bq, Qp);
        gemm16<0, half_t><<<gg, 256, 0, stream>>>(k16, W16 + NWELEM, bk, Kp);
        gemm16<2, half_t><<<gg, 256, 0, stream>>>(v16, W16 + 2 * (size_t)NWELEM, bv, VpT);

        attn_kernel<<<ga, 256, 0, stream>>>(Qp, Kp, VpT, Ob);

        gemm16<1, float><<<gg, 256, 0, stream>>>(Ob, W16 + 3 * (size_t)NWELEM, bo, out);
    } else {
        // legacy fallback path
        gemm_bt<0, float, half_t><<<ggL, 256, 0, stream>>>(query, Wq, bq, Qp);
        gemm_bt<0, float, half_t><<<ggL, 256, 0, stream>>>(key,   Wk, bk, Kp);
        gemm_bt<2, float, half_t><<<ggL, 256, 0, stream>>>(value, Wv, bv, VpT);
        attn_kernel<<<ga, 256, 0, stream>>>(Qp, Kp, VpT, Ob);
        gemm_bt<1, half_t, float><<<ggL, 256, 0, stream>>>(Ob, Wo, bo, out);
    }
}